// Round 9
// baseline (367.141 us; speedup 1.0000x reference)
//
#include <hip/hip_runtime.h>
#include <stdint.h>

#define DI __device__ __forceinline__

typedef __attribute__((ext_vector_type(8))) short bf16x8;
typedef __attribute__((ext_vector_type(4))) float f32x4;
typedef __attribute__((ext_vector_type(8))) unsigned short u16x8;
typedef __attribute__((ext_vector_type(2))) unsigned int u32x2;

static constexpr int BATCH = 4, SEQ = 2048, DIM = 1024, NH = 16, HDIM = 64, DOUT = 256;
static constexpr int MROWS = BATCH * SEQ;  // 8192

DI unsigned short f2b(float f) {
  union { float f; unsigned u; } v; v.f = f;
  unsigned u = v.u + 0x7FFFu + ((v.u >> 16) & 1u);
  return (unsigned short)(u >> 16);
}

DI float ex2(float x) {  // 2^x, single v_exp_f32
#if __has_builtin(__builtin_amdgcn_exp2f)
  return __builtin_amdgcn_exp2f(x);
#else
  float r; asm("v_exp_f32 %0, %1" : "=v"(r) : "v"(x)); return r;
#endif
}

typedef const __attribute__((address_space(1))) unsigned int* gp1;
typedef __attribute__((address_space(3))) unsigned int* lp3;
DI void gload16(const void* g, void* l) {
  __builtin_amdgcn_global_load_lds((gp1)g, (lp3)l, 16, 0, 0);
}

// ---------------- f32 -> bf16 convert (8 elems/thread) ----------------
__global__ void k_cvt(const float* __restrict__ s, unsigned short* __restrict__ d, int n8) {
  int i = blockIdx.x * 256 + threadIdx.x;
  if (i >= n8) return;
  const float4* sp = reinterpret_cast<const float4*>(s) + (size_t)i * 2;
  float4 a = sp[0], b = sp[1];
  u16x8 r;
  r[0] = f2b(a.x); r[1] = f2b(a.y); r[2] = f2b(a.z); r[3] = f2b(a.w);
  r[4] = f2b(b.x); r[5] = f2b(b.y); r[6] = f2b(b.z); r[7] = f2b(b.w);
  *reinterpret_cast<u16x8*>(d + (size_t)i * 8) = r;
}

// ---------------- f32 [R][C] -> bf16 [C][R] transpose-convert ----------------
__global__ void k_tcvt(const float* __restrict__ s, unsigned short* __restrict__ d, int R, int C) {
  __shared__ float t[32][33];
  int c0 = blockIdx.x * 32, r0 = blockIdx.y * 32;
  int tx = threadIdx.x, ty = threadIdx.y;  // block (32,8)
#pragma unroll
  for (int j = 0; j < 32; j += 8)
    t[ty + j][tx] = s[(size_t)(r0 + ty + j) * C + c0 + tx];
  __syncthreads();
#pragma unroll
  for (int j = 0; j < 32; j += 8)
    d[(size_t)(c0 + ty + j) * R + r0 + tx] = f2b(t[tx][ty + j]);
}

// ---------------- bf16 GEMM: A[M,K] x Bt[N,K]^T, 128x128 tile, BK=32 ----------------
// MODE 0: out bf16 [B,H,S,HD]   (n = h*64+hd, m = b*2048+s), v = (acc+bias)*scale
// MODE 1: out bf16 [B,H,HD,S]   (V transposed per head)
// MODE 2: out f32  [M,N] row-major
template <int MODE>
__global__ __launch_bounds__(256, 2) void k_gemm(
    const unsigned short* __restrict__ A, const unsigned short* __restrict__ Bt,
    const float* __restrict__ bias, void* __restrict__ out, int K, int N, float scale) {
  __shared__ unsigned short Al[128 * 32];
  __shared__ unsigned short Bl[128 * 32];
  const int tid = threadIdx.x, wid = tid >> 6, lane = tid & 63;
  const int m0 = blockIdx.x * 128, n0 = blockIdx.y * 128;
  const int wr = wid >> 1, wc = wid & 1;
  const int g = lane >> 4, r16 = lane & 15;

  f32x4 acc[4][4];
#pragma unroll
  for (int i = 0; i < 4; ++i)
#pragma unroll
    for (int j = 0; j < 4; ++j) acc[i][j] = f32x4{0.f, 0.f, 0.f, 0.f};

  for (int kk = 0; kk < K; kk += 32) {
#pragma unroll
    for (int is = 0; is < 2; ++is) {
      int slot = (is * 4 + wid) * 64 + lane;
      int row = slot >> 2, ch = slot & 3;
      gload16(A + (size_t)(m0 + row) * K + kk + ch * 8, &Al[(is * 4 + wid) * 64 * 8]);
    }
#pragma unroll
    for (int is = 0; is < 2; ++is) {
      int slot = (is * 4 + wid) * 64 + lane;
      int row = slot >> 2, ch = slot & 3;
      gload16(Bt + (size_t)(n0 + row) * K + kk + ch * 8, &Bl[(is * 4 + wid) * 64 * 8]);
    }
    __syncthreads();
    bf16x8 af[4], bfv[4];
#pragma unroll
    for (int i = 0; i < 4; ++i)
      af[i] = *reinterpret_cast<const bf16x8*>(&Al[(wr * 64 + i * 16 + r16) * 32 + g * 8]);
#pragma unroll
    for (int j = 0; j < 4; ++j)
      bfv[j] = *reinterpret_cast<const bf16x8*>(&Bl[(wc * 64 + j * 16 + r16) * 32 + g * 8]);
#pragma unroll
    for (int i = 0; i < 4; ++i)
#pragma unroll
      for (int j = 0; j < 4; ++j)
        acc[i][j] = __builtin_amdgcn_mfma_f32_16x16x32_bf16(af[i], bfv[j], acc[i][j], 0, 0, 0);
    __syncthreads();
  }

  const int rr = g * 4;
#pragma unroll
  for (int i = 0; i < 4; ++i) {
#pragma unroll
    for (int j = 0; j < 4; ++j) {
#pragma unroll
      for (int q = 0; q < 4; ++q) {
        int mrow = m0 + wr * 64 + i * 16 + rr + q;
        int ncol = n0 + wc * 64 + j * 16 + r16;
        float v = (acc[i][j][q] + bias[ncol]) * scale;
        if (MODE == 0) {
          int b_ = mrow >> 11, s_ = mrow & 2047;
          int h_ = ncol >> 6, hd = ncol & 63;
          ((unsigned short*)out)[(((size_t)(b_ * NH + h_) * SEQ + s_) << 6) + hd] = f2b(v);
        } else if (MODE == 1) {
          int b_ = mrow >> 11, s_ = mrow & 2047;
          int h_ = ncol >> 6, hd = ncol & 63;
          ((unsigned short*)out)[(((size_t)(b_ * NH + h_) * HDIM + hd) << 11) + s_] = f2b(v);
        } else {
          ((float*)out)[(size_t)mrow * N + ncol] = v;
        }
      }
    }
  }
}

// ---------------- attention with "+1" sink softmax, NO max subtraction ----------------
// P = exp2(S) directly (reference computes exp(x)/(1+sum) without max-sub; logits
// bounded). Row sums ride the matrix pipe via a ones-column B-fragment.
// SWAPPED QK^T: s = mfma(K_frag, Q_frag) -> D[kv][q]; each lane then holds 4
// CONSECUTIVE kv for one q-row, so the P store is 8x ds_write_b64 (packed pairs)
// instead of 32x ds_write_b16. Fragments are identical to the unswapped form.
// SINGLE-buffered K/V (dbuf measured neutral): LDS 32KB -> 5 blocks/CU; cross-block
// wave overlap hides the exposed stage latency. Pl rows stay wave-private (no B2).
__global__ __launch_bounds__(256, 5) void k_attn(
    const unsigned short* __restrict__ Qh, const unsigned short* __restrict__ Kh,
    const unsigned short* __restrict__ Vt, unsigned short* __restrict__ X) {
  __shared__ unsigned short Kl[64 * 64];   // [kv][hd], chunk-swizzled
  __shared__ unsigned short Vl[64 * 64];   // [hd][kv], chunk-swizzled
  __shared__ unsigned short Pl[128 * 64];  // [q][kv],  chunk-swizzled (wave-private rows)

  const int tid = threadIdx.x, wid = tid >> 6, lane = tid & 63;
  const int g = lane >> 4, r16 = lane & 15;
  const int bh = blockIdx.y, b_ = bh >> 4, h_ = bh & 15;
  const int q0 = blockIdx.x * 128;
  const unsigned short* Qp = Qh + ((size_t)bh * SEQ + q0) * HDIM;
  const unsigned short* Kp = Kh + (size_t)bh * SEQ * HDIM;
  const unsigned short* Vp = Vt + (size_t)bh * HDIM * SEQ;
  const int qw = wid * 32;

  // Q fragments (dual-use: row/col = lane&15 -> q, k = hd = ks*32+g*8..)
  bf16x8 qf[2][2];
#pragma unroll
  for (int fr = 0; fr < 2; ++fr)
#pragma unroll
    for (int ks = 0; ks < 2; ++ks)
      qf[fr][ks] = *reinterpret_cast<const bf16x8*>(
          Qp + (size_t)(qw + fr * 16 + r16) * HDIM + ks * 32 + g * 8);

  // ones B-fragment: col 0 = 1.0 (bf16 0x3F80) -> D[:,0] = row sums of P
  bf16x8 vones;
#pragma unroll
  for (int i = 0; i < 8; ++i) vones[i] = (r16 == 0) ? (short)0x3F80 : (short)0;

  // staging source offsets (swizzled source chunks; LDS dest wave-linear)
  const int slot0 = wid * 64 + lane, slot1 = (4 + wid) * 64 + lane;
  const int sr0 = slot0 >> 3, sc0 = (slot0 & 7) ^ (sr0 & 7);
  const int sr1 = slot1 >> 3, sc1 = (slot1 & 7) ^ (sr1 & 7);
  const unsigned short* Ks0 = Kp + (size_t)sr0 * HDIM + sc0 * 8;
  const unsigned short* Ks1 = Kp + (size_t)sr1 * HDIM + sc1 * 8;
  const unsigned short* Vs0 = Vp + (size_t)sr0 * SEQ + sc0 * 8;
  const unsigned short* Vs1 = Vp + (size_t)sr1 * SEQ + sc1 * 8;
  const int ld0 = wid * 512, ld1 = (4 + wid) * 512;

  f32x4 o[2][4], ol[2];
#pragma unroll
  for (int fr = 0; fr < 2; ++fr) {
#pragma unroll
    for (int hf = 0; hf < 4; ++hf) o[fr][hf] = f32x4{0.f, 0.f, 0.f, 0.f};
    ol[fr] = f32x4{0.f, 0.f, 0.f, 0.f};
  }

  for (int t = 0; t < SEQ / 64; ++t) {
    __syncthreads();  // WAR: all waves done reading tile t-1 from Kl/Vl
    {
      const size_t koff = (size_t)t * 64 * HDIM;
      const int voff = t * 64;
      gload16(Ks0 + koff, &Kl[ld0]);
      gload16(Ks1 + koff, &Kl[ld1]);
      gload16(Vs0 + voff, &Vl[ld0]);
      gload16(Vs1 + voff, &Vl[ld1]);
    }
    __syncthreads();  // RAW: barrier drains vmcnt -> tile t visible to all waves

    // S^T = K Q^T: A = K rows kv, B = Q cols q -> D[kv][q]
    // lane holds S[kv = cf*16 + g*4 + reg][q = fr*16 + r16]
    f32x4 s_[2][4];
#pragma unroll
    for (int fr = 0; fr < 2; ++fr)
#pragma unroll
      for (int cf = 0; cf < 4; ++cf) s_[fr][cf] = f32x4{0.f, 0.f, 0.f, 0.f};
#pragma unroll
    for (int cf = 0; cf < 4; ++cf) {
      int krow = cf * 16 + r16;
#pragma unroll
      for (int ks = 0; ks < 2; ++ks) {
        bf16x8 kf = *reinterpret_cast<const bf16x8*>(
            &Kl[krow * 64 + (((ks * 4 + g) ^ (krow & 7)) << 3)]);
#pragma unroll
        for (int fr = 0; fr < 2; ++fr)
          s_[fr][cf] = __builtin_amdgcn_mfma_f32_16x16x32_bf16(kf, qf[fr][ks], s_[fr][cf], 0, 0, 0);
      }
    }

    // P = exp2(S) (no max subtraction); pack 4 consecutive kv -> one b64 LDS write
#pragma unroll
    for (int fr = 0; fr < 2; ++fr) {
      int prow = qw + fr * 16 + r16;
      int base = prow * 64, swz = prow & 7;
#pragma unroll
      for (int cf = 0; cf < 4; ++cf) {
        float p0 = ex2(s_[fr][cf][0]);
        float p1 = ex2(s_[fr][cf][1]);
        float p2 = ex2(s_[fr][cf][2]);
        float p3 = ex2(s_[fr][cf][3]);
        unsigned w0 = (unsigned)f2b(p0) | ((unsigned)f2b(p1) << 16);
        unsigned w1 = (unsigned)f2b(p2) | ((unsigned)f2b(p3) << 16);
        int off = base + (((cf * 2 + (g >> 1)) ^ swz) << 3) + (g & 1) * 4;
        *reinterpret_cast<u32x2*>(&Pl[off]) = u32x2{w0, w1};
      }
    }
    // (no barrier: Pl rows wave-private; same-wave LDS RAW ordered by lgkmcnt)

    // O += P V ; l += P 1  (A = P rows q; B = V cols hd from Vt rows / ones col)
#pragma unroll
    for (int ks = 0; ks < 2; ++ks) {
      bf16x8 pf[2];
#pragma unroll
      for (int fr = 0; fr < 2; ++fr) {
        int prow = qw + fr * 16 + r16;
        pf[fr] = *reinterpret_cast<const bf16x8*>(
            &Pl[prow * 64 + (((ks * 4 + g) ^ (prow & 7)) << 3)]);
      }
#pragma unroll
      for (int hf = 0; hf < 4; ++hf) {
        int vrow = hf * 16 + r16;
        bf16x8 vf = *reinterpret_cast<const bf16x8*>(
            &Vl[vrow * 64 + (((ks * 4 + g) ^ (vrow & 7)) << 3)]);
#pragma unroll
        for (int fr = 0; fr < 2; ++fr)
          o[fr][hf] = __builtin_amdgcn_mfma_f32_16x16x32_bf16(pf[fr], vf, o[fr][hf], 0, 0, 0);
      }
#pragma unroll
      for (int fr = 0; fr < 2; ++fr)
        ol[fr] = __builtin_amdgcn_mfma_f32_16x16x32_bf16(pf[fr], vones, ol[fr], 0, 0, 0);
    }
  }

  // epilogue: l for row 4g+q lives in lane (g,0) reg q; sink adds 1. Write X.
#pragma unroll
  for (int fr = 0; fr < 2; ++fr) {
#pragma unroll
    for (int q = 0; q < 4; ++q) {
      float lsum = __shfl(ol[fr][q], lane & 48, 64);
      float inv = 1.0f / (1.0f + lsum);
      int row = q0 + qw + fr * 16 + g * 4 + q;
      unsigned short* xp = X + (size_t)(b_ * SEQ + row) * DIM + h_ * 64;
#pragma unroll
      for (int hf = 0; hf < 4; ++hf) xp[hf * 16 + r16] = f2b(o[fr][hf][q] * inv);
    }
  }
}

extern "C" void kernel_launch(void* const* d_in, const int* in_sizes, int n_in,
                              void* d_out, int out_size, void* d_ws, size_t ws_size,
                              hipStream_t stream) {
  const float* q  = (const float*)d_in[0];
  const float* k  = (const float*)d_in[1];
  const float* v  = (const float*)d_in[2];
  const float* Wq = (const float*)d_in[3];
  const float* bq = (const float*)d_in[4];
  const float* Wk = (const float*)d_in[5];
  const float* bk = (const float*)d_in[6];
  const float* Wv = (const float*)d_in[7];
  const float* bv = (const float*)d_in[8];
  const float* Wf = (const float*)d_in[9];
  const float* bf = (const float*)d_in[10];

  char* ws = (char*)d_ws;
  unsigned short* Abuf = (unsigned short*)ws;                              // 8192*1024 bf16 (also attn X)
  unsigned short* Wt   = (unsigned short*)(ws + (size_t)16777216);         // up to 1024*1024 bf16
  unsigned short* Qh   = (unsigned short*)(ws + (size_t)16777216 + 2097152);
  unsigned short* Kh   = Qh + (size_t)MROWS * DIM;
  unsigned short* Vtb  = Kh + (size_t)MROWS * DIM;

  dim3 cvtg(4096), b256(256);
  dim3 tb(32, 8);
  dim3 gemmg(64, 8);
  dim3 attng(16, 64);
  dim3 fing(64, 2);

  const int n8 = MROWS * DIM / 8;
  const float qscale = 0.125f * 1.44269504088896f;  // 1/sqrt(64) * log2(e): S in log2 units

  // Q path
  k_cvt<<<cvtg, b256, 0, stream>>>(q, Abuf, n8);
  k_tcvt<<<dim3(32, 32), tb, 0, stream>>>(Wq, Wt, DIM, DIM);
  k_gemm<0><<<gemmg, b256, 0, stream>>>(Abuf, Wt, bq, (void*)Qh, DIM, DIM, qscale);
  // K path
  k_cvt<<<cvtg, b256, 0, stream>>>(k, Abuf, n8);
  k_tcvt<<<dim3(32, 32), tb, 0, stream>>>(Wk, Wt, DIM, DIM);
  k_gemm<0><<<gemmg, b256, 0, stream>>>(Abuf, Wt, bk, (void*)Kh, DIM, DIM, 1.0f);
  // V path (stored transposed per head)
  k_cvt<<<cvtg, b256, 0, stream>>>(v, Abuf, n8);
  k_tcvt<<<dim3(32, 32), tb, 0, stream>>>(Wv, Wt, DIM, DIM);
  k_gemm<1><<<gemmg, b256, 0, stream>>>(Abuf, Wt, bv, (void*)Vtb, DIM, DIM, 1.0f);
  // attention -> X (reuse Abuf)
  k_attn<<<attng, b256, 0, stream>>>(Qh, Kh, Vtb, Abuf);
  // final projection -> f32 out
  k_tcvt<<<dim3(8, 32), tb, 0, stream>>>(Wf, Wt, DIM, DOUT);
  k_gemm<2><<<fing, b256, 0, stream>>>(Abuf, Wt, bf, d_out, DIM, DOUT, 1.0f);
}

// Round 11
// 228.430 us; speedup vs baseline: 1.6072x; 1.6072x over previous
//
#include <hip/hip_runtime.h>
#include <stdint.h>

#define DI __device__ __forceinline__

typedef __attribute__((ext_vector_type(8))) short bf16x8;
typedef __attribute__((ext_vector_type(4))) float f32x4;
typedef __attribute__((ext_vector_type(8))) unsigned short u16x8;
typedef __attribute__((ext_vector_type(2))) unsigned int u32x2;

static constexpr int BATCH = 4, SEQ = 2048, DIM = 1024, NH = 16, HDIM = 64, DOUT = 256;
static constexpr int MROWS = BATCH * SEQ;  // 8192

DI unsigned short f2b(float f) {
  union { float f; unsigned u; } v; v.f = f;
  unsigned u = v.u + 0x7FFFu + ((v.u >> 16) & 1u);
  return (unsigned short)(u >> 16);
}

DI float ex2(float x) {  // 2^x, single v_exp_f32
#if __has_builtin(__builtin_amdgcn_exp2f)
  return __builtin_amdgcn_exp2f(x);
#else
  float r; asm("v_exp_f32 %0, %1" : "=v"(r) : "v"(x)); return r;
#endif
}

typedef const __attribute__((address_space(1))) unsigned int* gp1;
typedef __attribute__((address_space(3))) unsigned int* lp3;
DI void gload16(const void* g, void* l) {
  __builtin_amdgcn_global_load_lds((gp1)g, (lp3)l, 16, 0, 0);
}

// ---------------- f32 -> bf16 convert (8 elems/thread) ----------------
__global__ void k_cvt(const float* __restrict__ s, unsigned short* __restrict__ d, int n8) {
  int i = blockIdx.x * 256 + threadIdx.x;
  if (i >= n8) return;
  const float4* sp = reinterpret_cast<const float4*>(s) + (size_t)i * 2;
  float4 a = sp[0], b = sp[1];
  u16x8 r;
  r[0] = f2b(a.x); r[1] = f2b(a.y); r[2] = f2b(a.z); r[3] = f2b(a.w);
  r[4] = f2b(b.x); r[5] = f2b(b.y); r[6] = f2b(b.z); r[7] = f2b(b.w);
  *reinterpret_cast<u16x8*>(d + (size_t)i * 8) = r;
}

// ---------------- f32 [R][C] -> bf16 [C][R] transpose-convert ----------------
__global__ void k_tcvt(const float* __restrict__ s, unsigned short* __restrict__ d, int R, int C) {
  __shared__ float t[32][33];
  int c0 = blockIdx.x * 32, r0 = blockIdx.y * 32;
  int tx = threadIdx.x, ty = threadIdx.y;  // block (32,8)
#pragma unroll
  for (int j = 0; j < 32; j += 8)
    t[ty + j][tx] = s[(size_t)(r0 + ty + j) * C + c0 + tx];
  __syncthreads();
#pragma unroll
  for (int j = 0; j < 32; j += 8)
    d[(size_t)(c0 + ty + j) * R + r0 + tx] = f2b(t[tx][ty + j]);
}

// ---------------- bf16 GEMM: A[M,K] x Bt[N,K]^T, 128x128 tile, BK=32 ----------------
// MODE 0: out bf16 [B,H,S,HD]   (n = h*64+hd, m = b*2048+s), v = (acc+bias)*scale
// MODE 1: out bf16 [B,H,HD,S]   (V transposed per head)
// MODE 2: out f32  [M,N] row-major
template <int MODE>
__global__ __launch_bounds__(256, 2) void k_gemm(
    const unsigned short* __restrict__ A, const unsigned short* __restrict__ Bt,
    const float* __restrict__ bias, void* __restrict__ out, int K, int N, float scale) {
  __shared__ unsigned short Al[128 * 32];
  __shared__ unsigned short Bl[128 * 32];
  const int tid = threadIdx.x, wid = tid >> 6, lane = tid & 63;
  const int m0 = blockIdx.x * 128, n0 = blockIdx.y * 128;
  const int wr = wid >> 1, wc = wid & 1;
  const int g = lane >> 4, r16 = lane & 15;

  f32x4 acc[4][4];
#pragma unroll
  for (int i = 0; i < 4; ++i)
#pragma unroll
    for (int j = 0; j < 4; ++j) acc[i][j] = f32x4{0.f, 0.f, 0.f, 0.f};

  for (int kk = 0; kk < K; kk += 32) {
#pragma unroll
    for (int is = 0; is < 2; ++is) {
      int slot = (is * 4 + wid) * 64 + lane;
      int row = slot >> 2, ch = slot & 3;
      gload16(A + (size_t)(m0 + row) * K + kk + ch * 8, &Al[(is * 4 + wid) * 64 * 8]);
    }
#pragma unroll
    for (int is = 0; is < 2; ++is) {
      int slot = (is * 4 + wid) * 64 + lane;
      int row = slot >> 2, ch = slot & 3;
      gload16(Bt + (size_t)(n0 + row) * K + kk + ch * 8, &Bl[(is * 4 + wid) * 64 * 8]);
    }
    __syncthreads();
    bf16x8 af[4], bfv[4];
#pragma unroll
    for (int i = 0; i < 4; ++i)
      af[i] = *reinterpret_cast<const bf16x8*>(&Al[(wr * 64 + i * 16 + r16) * 32 + g * 8]);
#pragma unroll
    for (int j = 0; j < 4; ++j)
      bfv[j] = *reinterpret_cast<const bf16x8*>(&Bl[(wc * 64 + j * 16 + r16) * 32 + g * 8]);
#pragma unroll
    for (int i = 0; i < 4; ++i)
#pragma unroll
      for (int j = 0; j < 4; ++j)
        acc[i][j] = __builtin_amdgcn_mfma_f32_16x16x32_bf16(af[i], bfv[j], acc[i][j], 0, 0, 0);
    __syncthreads();
  }

  const int rr = g * 4;
#pragma unroll
  for (int i = 0; i < 4; ++i) {
#pragma unroll
    for (int j = 0; j < 4; ++j) {
#pragma unroll
      for (int q = 0; q < 4; ++q) {
        int mrow = m0 + wr * 64 + i * 16 + rr + q;
        int ncol = n0 + wc * 64 + j * 16 + r16;
        float v = (acc[i][j][q] + bias[ncol]) * scale;
        if (MODE == 0) {
          int b_ = mrow >> 11, s_ = mrow & 2047;
          int h_ = ncol >> 6, hd = ncol & 63;
          ((unsigned short*)out)[(((size_t)(b_ * NH + h_) * SEQ + s_) << 6) + hd] = f2b(v);
        } else if (MODE == 1) {
          int b_ = mrow >> 11, s_ = mrow & 2047;
          int h_ = ncol >> 6, hd = ncol & 63;
          ((unsigned short*)out)[(((size_t)(b_ * NH + h_) * HDIM + hd) << 11) + s_] = f2b(v);
        } else {
          ((float*)out)[(size_t)mrow * N + ncol] = v;
        }
      }
    }
  }
}

// ---------------- attention with "+1" sink softmax, NO max subtraction ----------------
// P = exp2(S) directly (reference computes exp(x)/(1+sum) without max-sub; logits
// bounded). Row sums ride the matrix pipe via a ones-column B-fragment.
// SWAPPED QK^T: s = mfma(K_frag, Q_frag) -> D[kv][q]; lane holds 4 consecutive kv
// per q-row -> P store is 8x ds_write_b64 instead of 32x ds_write_b16.
// Single-buffered K/V: 32KB LDS. __launch_bounds__(256,4): VGPR cap 128 (the
// (256,5) cap of ~102 forced a spill to scratch -> 3.3x FETCH blowup in r9).
__global__ __launch_bounds__(256, 4) void k_attn(
    const unsigned short* __restrict__ Qh, const unsigned short* __restrict__ Kh,
    const unsigned short* __restrict__ Vt, unsigned short* __restrict__ X) {
  __shared__ unsigned short Kl[64 * 64];   // [kv][hd], chunk-swizzled
  __shared__ unsigned short Vl[64 * 64];   // [hd][kv], chunk-swizzled
  __shared__ unsigned short Pl[128 * 64];  // [q][kv],  chunk-swizzled (wave-private rows)

  const int tid = threadIdx.x, wid = tid >> 6, lane = tid & 63;
  const int g = lane >> 4, r16 = lane & 15;
  const int bh = blockIdx.y, b_ = bh >> 4, h_ = bh & 15;
  const int q0 = blockIdx.x * 128;
  const unsigned short* Qp = Qh + ((size_t)bh * SEQ + q0) * HDIM;
  const unsigned short* Kp = Kh + (size_t)bh * SEQ * HDIM;
  const unsigned short* Vp = Vt + (size_t)bh * HDIM * SEQ;
  const int qw = wid * 32;

  // Q fragments (row/col = lane&15 -> q, k = hd = ks*32+g*8..)
  bf16x8 qf[2][2];
#pragma unroll
  for (int fr = 0; fr < 2; ++fr)
#pragma unroll
    for (int ks = 0; ks < 2; ++ks)
      qf[fr][ks] = *reinterpret_cast<const bf16x8*>(
          Qp + (size_t)(qw + fr * 16 + r16) * HDIM + ks * 32 + g * 8);

  // ones B-fragment: col 0 = 1.0 (bf16 0x3F80) -> D[:,0] = row sums of P
  bf16x8 vones;
#pragma unroll
  for (int i = 0; i < 8; ++i) vones[i] = (r16 == 0) ? (short)0x3F80 : (short)0;

  // staging source offsets (swizzled source chunks; LDS dest wave-linear)
  const int slot0 = wid * 64 + lane, slot1 = (4 + wid) * 64 + lane;
  const int sr0 = slot0 >> 3, sc0 = (slot0 & 7) ^ (sr0 & 7);
  const int sr1 = slot1 >> 3, sc1 = (slot1 & 7) ^ (sr1 & 7);
  const unsigned short* Ks0 = Kp + (size_t)sr0 * HDIM + sc0 * 8;
  const unsigned short* Ks1 = Kp + (size_t)sr1 * HDIM + sc1 * 8;
  const unsigned short* Vs0 = Vp + (size_t)sr0 * SEQ + sc0 * 8;
  const unsigned short* Vs1 = Vp + (size_t)sr1 * SEQ + sc1 * 8;
  const int ld0 = wid * 512, ld1 = (4 + wid) * 512;

  f32x4 o[2][4], ol[2];
#pragma unroll
  for (int fr = 0; fr < 2; ++fr) {
#pragma unroll
    for (int hf = 0; hf < 4; ++hf) o[fr][hf] = f32x4{0.f, 0.f, 0.f, 0.f};
    ol[fr] = f32x4{0.f, 0.f, 0.f, 0.f};
  }

  for (int t = 0; t < SEQ / 64; ++t) {
    __syncthreads();  // WAR: all waves done reading tile t-1 from Kl/Vl
    {
      const size_t koff = (size_t)t * 64 * HDIM;
      const int voff = t * 64;
      gload16(Ks0 + koff, &Kl[ld0]);
      gload16(Ks1 + koff, &Kl[ld1]);
      gload16(Vs0 + voff, &Vl[ld0]);
      gload16(Vs1 + voff, &Vl[ld1]);
    }
    __syncthreads();  // RAW: barrier drains vmcnt -> tile t visible to all waves

    // S^T = K Q^T: A = K rows kv, B = Q cols q -> D[kv][q]
    // lane holds S[kv = cf*16 + g*4 + reg][q = fr*16 + r16]
    f32x4 s_[2][4];
#pragma unroll
    for (int fr = 0; fr < 2; ++fr)
#pragma unroll
      for (int cf = 0; cf < 4; ++cf) s_[fr][cf] = f32x4{0.f, 0.f, 0.f, 0.f};
#pragma unroll
    for (int cf = 0; cf < 4; ++cf) {
      int krow = cf * 16 + r16;
#pragma unroll
      for (int ks = 0; ks < 2; ++ks) {
        bf16x8 kf = *reinterpret_cast<const bf16x8*>(
            &Kl[krow * 64 + (((ks * 4 + g) ^ (krow & 7)) << 3)]);
#pragma unroll
        for (int fr = 0; fr < 2; ++fr)
          s_[fr][cf] = __builtin_amdgcn_mfma_f32_16x16x32_bf16(kf, qf[fr][ks], s_[fr][cf], 0, 0, 0);
      }
    }

    // P = exp2(S) (no max subtraction); pack 4 consecutive kv -> one b64 LDS write
#pragma unroll
    for (int fr = 0; fr < 2; ++fr) {
      int prow = qw + fr * 16 + r16;
      int base = prow * 64, swz = prow & 7;
#pragma unroll
      for (int cf = 0; cf < 4; ++cf) {
        float p0 = ex2(s_[fr][cf][0]);
        float p1 = ex2(s_[fr][cf][1]);
        float p2 = ex2(s_[fr][cf][2]);
        float p3 = ex2(s_[fr][cf][3]);
        unsigned w0 = (unsigned)f2b(p0) | ((unsigned)f2b(p1) << 16);
        unsigned w1 = (unsigned)f2b(p2) | ((unsigned)f2b(p3) << 16);
        int off = base + (((cf * 2 + (g >> 1)) ^ swz) << 3) + (g & 1) * 4;
        *reinterpret_cast<u32x2*>(&Pl[off]) = u32x2{w0, w1};
      }
    }
    // (no barrier: Pl rows wave-private; same-wave LDS RAW ordered by lgkmcnt)

    // O += P V ; l += P 1  (A = P rows q; B = V cols hd from Vt rows / ones col)
#pragma unroll
    for (int ks = 0; ks < 2; ++ks) {
      bf16x8 pf[2];
#pragma unroll
      for (int fr = 0; fr < 2; ++fr) {
        int prow = qw + fr * 16 + r16;
        pf[fr] = *reinterpret_cast<const bf16x8*>(
            &Pl[prow * 64 + (((ks * 4 + g) ^ (prow & 7)) << 3)]);
      }
#pragma unroll
      for (int hf = 0; hf < 4; ++hf) {
        int vrow = hf * 16 + r16;
        bf16x8 vf = *reinterpret_cast<const bf16x8*>(
            &Vl[vrow * 64 + (((ks * 4 + g) ^ (vrow & 7)) << 3)]);
#pragma unroll
        for (int fr = 0; fr < 2; ++fr)
          o[fr][hf] = __builtin_amdgcn_mfma_f32_16x16x32_bf16(pf[fr], vf, o[fr][hf], 0, 0, 0);
      }
#pragma unroll
      for (int fr = 0; fr < 2; ++fr)
        ol[fr] = __builtin_amdgcn_mfma_f32_16x16x32_bf16(pf[fr], vones, ol[fr], 0, 0, 0);
    }
  }

  // epilogue: l for row 4g+q lives in lane (g,0) reg q; sink adds 1. Write X.
#pragma unroll
  for (int fr = 0; fr < 2; ++fr) {
#pragma unroll
    for (int q = 0; q < 4; ++q) {
      float lsum = __shfl(ol[fr][q], lane & 48, 64);
      float inv = 1.0f / (1.0f + lsum);
      int row = q0 + qw + fr * 16 + g * 4 + q;
      unsigned short* xp = X + (size_t)(b_ * SEQ + row) * DIM + h_ * 64;
#pragma unroll
      for (int hf = 0; hf < 4; ++hf) xp[hf * 16 + r16] = f2b(o[fr][hf][q] * inv);
    }
  }
}

extern "C" void kernel_launch(void* const* d_in, const int* in_sizes, int n_in,
                              void* d_out, int out_size, void* d_ws, size_t ws_size,
                              hipStream_t stream) {
  const float* q  = (const float*)d_in[0];
  const float* k  = (const float*)d_in[1];
  const float* v  = (const float*)d_in[2];
  const float* Wq = (const float*)d_in[3];
  const float* bq = (const float*)d_in[4];
  const float* Wk = (const float*)d_in[5];
  const float* bk = (const float*)d_in[6];
  const float* Wv = (const float*)d_in[7];
  const float* bv = (const float*)d_in[8];
  const float* Wf = (const float*)d_in[9];
  const float* bf = (const float*)d_in[10];

  char* ws = (char*)d_ws;
  unsigned short* Abuf = (unsigned short*)ws;                              // 8192*1024 bf16 (also attn X)
  unsigned short* Wt   = (unsigned short*)(ws + (size_t)16777216);         // up to 1024*1024 bf16
  unsigned short* Qh   = (unsigned short*)(ws + (size_t)16777216 + 2097152);
  unsigned short* Kh   = Qh + (size_t)MROWS * DIM;
  unsigned short* Vtb  = Kh + (size_t)MROWS * DIM;

  dim3 cvtg(4096), b256(256);
  dim3 tb(32, 8);
  dim3 gemmg(64, 8);
  dim3 attng(16, 64);
  dim3 fing(64, 2);

  const int n8 = MROWS * DIM / 8;
  const float qscale = 0.125f * 1.44269504088896f;  // 1/sqrt(64) * log2(e): S in log2 units

  // Q path
  k_cvt<<<cvtg, b256, 0, stream>>>(q, Abuf, n8);
  k_tcvt<<<dim3(32, 32), tb, 0, stream>>>(Wq, Wt, DIM, DIM);
  k_gemm<0><<<gemmg, b256, 0, stream>>>(Abuf, Wt, bq, (void*)Qh, DIM, DIM, qscale);
  // K path
  k_cvt<<<cvtg, b256, 0, stream>>>(k, Abuf, n8);
  k_tcvt<<<dim3(32, 32), tb, 0, stream>>>(Wk, Wt, DIM, DIM);
  k_gemm<0><<<gemmg, b256, 0, stream>>>(Abuf, Wt, bk, (void*)Kh, DIM, DIM, 1.0f);
  // V path (stored transposed per head)
  k_cvt<<<cvtg, b256, 0, stream>>>(v, Abuf, n8);
  k_tcvt<<<dim3(32, 32), tb, 0, stream>>>(Wv, Wt, DIM, DIM);
  k_gemm<1><<<gemmg, b256, 0, stream>>>(Abuf, Wt, bv, (void*)Vtb, DIM, DIM, 1.0f);
  // attention -> X (reuse Abuf)
  k_attn<<<attng, b256, 0, stream>>>(Qh, Kh, Vtb, Abuf);
  // final projection -> f32 out
  k_tcvt<<<dim3(8, 32), tb, 0, stream>>>(Wf, Wt, DIM, DOUT);
  k_gemm<2><<<fing, b256, 0, stream>>>(Abuf, Wt, bf, d_out, DIM, DOUT, 1.0f);
}

// Round 14
// 216.776 us; speedup vs baseline: 1.6936x; 1.0538x over previous
//
#include <hip/hip_runtime.h>
#include <stdint.h>

#define DI __device__ __forceinline__

typedef __attribute__((ext_vector_type(8))) short bf16x8;
typedef __attribute__((ext_vector_type(4))) float f32x4;
typedef __attribute__((ext_vector_type(8))) unsigned short u16x8;
typedef __attribute__((ext_vector_type(2))) unsigned int u32x2;

static constexpr int BATCH = 4, SEQ = 2048, DIM = 1024, NH = 16, HDIM = 64, DOUT = 256;
static constexpr int MROWS = BATCH * SEQ;  // 8192

DI unsigned short f2b(float f) {
  union { float f; unsigned u; } v; v.f = f;
  unsigned u = v.u + 0x7FFFu + ((v.u >> 16) & 1u);
  return (unsigned short)(u >> 16);
}

DI float ex2(float x) {  // 2^x, single v_exp_f32
#if __has_builtin(__builtin_amdgcn_exp2f)
  return __builtin_amdgcn_exp2f(x);
#else
  float r; asm("v_exp_f32 %0, %1" : "=v"(r) : "v"(x)); return r;
#endif
}

DI unsigned cvtpk(float lo, float hi) {  // packed bf16(lo) | bf16(hi)<<16
  unsigned r; asm("v_cvt_pk_bf16_f32 %0, %1, %2" : "=v"(r) : "v"(lo), "v"(hi)); return r;
}

typedef const __attribute__((address_space(1))) unsigned int* gp1;
typedef __attribute__((address_space(3))) unsigned int* lp3;
DI void gload16(const void* g, void* l) {
  __builtin_amdgcn_global_load_lds((gp1)g, (lp3)l, 16, 0, 0);
}

// ---------------- f32 -> bf16 convert (8 elems/thread) ----------------
__global__ void k_cvt(const float* __restrict__ s, unsigned short* __restrict__ d, int n8) {
  int i = blockIdx.x * 256 + threadIdx.x;
  if (i >= n8) return;
  const float4* sp = reinterpret_cast<const float4*>(s) + (size_t)i * 2;
  float4 a = sp[0], b = sp[1];
  u16x8 r;
  r[0] = f2b(a.x); r[1] = f2b(a.y); r[2] = f2b(a.z); r[3] = f2b(a.w);
  r[4] = f2b(b.x); r[5] = f2b(b.y); r[6] = f2b(b.z); r[7] = f2b(b.w);
  *reinterpret_cast<u16x8*>(d + (size_t)i * 8) = r;
}

// ---------------- f32 [R][C] -> bf16 [C][R] transpose-convert ----------------
__global__ void k_tcvt(const float* __restrict__ s, unsigned short* __restrict__ d, int R, int C) {
  __shared__ float t[32][33];
  int c0 = blockIdx.x * 32, r0 = blockIdx.y * 32;
  int tx = threadIdx.x, ty = threadIdx.y;  // block (32,8)
#pragma unroll
  for (int j = 0; j < 32; j += 8)
    t[ty + j][tx] = s[(size_t)(r0 + ty + j) * C + c0 + tx];
  __syncthreads();
#pragma unroll
  for (int j = 0; j < 32; j += 8)
    d[(size_t)(c0 + ty + j) * R + r0 + tx] = f2b(t[tx][ty + j]);
}

// ---------------- bf16 GEMM: A[M,K] x Bt[N,K]^T, 128x128 tile, BK=32 ----------------
// MODE 0: out bf16 [B,H,S,HD]   (n = h*64+hd, m = b*2048+s), v = (acc+bias)*scale
// MODE 1: out bf16 [B,H,HD,S]   (V transposed per head)
// MODE 2: out f32  [M,N] row-major
template <int MODE>
__global__ __launch_bounds__(256, 2) void k_gemm(
    const unsigned short* __restrict__ A, const unsigned short* __restrict__ Bt,
    const float* __restrict__ bias, void* __restrict__ out, int K, int N, float scale) {
  __shared__ unsigned short Al[128 * 32];
  __shared__ unsigned short Bl[128 * 32];
  const int tid = threadIdx.x, wid = tid >> 6, lane = tid & 63;
  const int m0 = blockIdx.x * 128, n0 = blockIdx.y * 128;
  const int wr = wid >> 1, wc = wid & 1;
  const int g = lane >> 4, r16 = lane & 15;

  f32x4 acc[4][4];
#pragma unroll
  for (int i = 0; i < 4; ++i)
#pragma unroll
    for (int j = 0; j < 4; ++j) acc[i][j] = f32x4{0.f, 0.f, 0.f, 0.f};

  for (int kk = 0; kk < K; kk += 32) {
#pragma unroll
    for (int is = 0; is < 2; ++is) {
      int slot = (is * 4 + wid) * 64 + lane;
      int row = slot >> 2, ch = slot & 3;
      gload16(A + (size_t)(m0 + row) * K + kk + ch * 8, &Al[(is * 4 + wid) * 64 * 8]);
    }
#pragma unroll
    for (int is = 0; is < 2; ++is) {
      int slot = (is * 4 + wid) * 64 + lane;
      int row = slot >> 2, ch = slot & 3;
      gload16(Bt + (size_t)(n0 + row) * K + kk + ch * 8, &Bl[(is * 4 + wid) * 64 * 8]);
    }
    __syncthreads();
    bf16x8 af[4], bfv[4];
#pragma unroll
    for (int i = 0; i < 4; ++i)
      af[i] = *reinterpret_cast<const bf16x8*>(&Al[(wr * 64 + i * 16 + r16) * 32 + g * 8]);
#pragma unroll
    for (int j = 0; j < 4; ++j)
      bfv[j] = *reinterpret_cast<const bf16x8*>(&Bl[(wc * 64 + j * 16 + r16) * 32 + g * 8]);
#pragma unroll
    for (int i = 0; i < 4; ++i)
#pragma unroll
      for (int j = 0; j < 4; ++j)
        acc[i][j] = __builtin_amdgcn_mfma_f32_16x16x32_bf16(af[i], bfv[j], acc[i][j], 0, 0, 0);
    __syncthreads();
  }

  const int rr = g * 4;
#pragma unroll
  for (int i = 0; i < 4; ++i) {
#pragma unroll
    for (int j = 0; j < 4; ++j) {
#pragma unroll
      for (int q = 0; q < 4; ++q) {
        int mrow = m0 + wr * 64 + i * 16 + rr + q;
        int ncol = n0 + wc * 64 + j * 16 + r16;
        float v = (acc[i][j][q] + bias[ncol]) * scale;
        if (MODE == 0) {
          int b_ = mrow >> 11, s_ = mrow & 2047;
          int h_ = ncol >> 6, hd = ncol & 63;
          ((unsigned short*)out)[(((size_t)(b_ * NH + h_) * SEQ + s_) << 6) + hd] = f2b(v);
        } else if (MODE == 1) {
          int b_ = mrow >> 11, s_ = mrow & 2047;
          int h_ = ncol >> 6, hd = ncol & 63;
          ((unsigned short*)out)[(((size_t)(b_ * NH + h_) * HDIM + hd) << 11) + s_] = f2b(v);
        } else {
          ((float*)out)[(size_t)mrow * N + ncol] = v;
        }
      }
    }
  }
}

// ---------------- attention with "+1" sink softmax, NO max subtraction ----------------
// P = exp2(S) directly (reference computes exp(x)/(1+sum) without max-sub; logits
// bounded). Row sums ride the matrix pipe via a ones-column B-fragment.
// SWAPPED QK^T: s = mfma(K_frag, Q_frag) -> D[kv][q]; lane holds 4 consecutive kv
// per q-row. P store: 16x v_cvt_pk_bf16_f32 + 8x ds_write_b64 per tile (was 32x
// f2b = ~112 extra VALU ops -- VALUBusy 49% was the measured limiter in r11).
// Single-buffered K/V: 32KB LDS, __launch_bounds__(256,4) (r9: (256,5) spilled).
__global__ __launch_bounds__(256, 4) void k_attn(
    const unsigned short* __restrict__ Qh, const unsigned short* __restrict__ Kh,
    const unsigned short* __restrict__ Vt, unsigned short* __restrict__ X) {
  __shared__ unsigned short Kl[64 * 64];   // [kv][hd], chunk-swizzled
  __shared__ unsigned short Vl[64 * 64];   // [hd][kv], chunk-swizzled
  __shared__ unsigned short Pl[128 * 64];  // [q][kv],  chunk-swizzled (wave-private rows)

  const int tid = threadIdx.x, wid = tid >> 6, lane = tid & 63;
  const int g = lane >> 4, r16 = lane & 15;
  const int bh = blockIdx.y, b_ = bh >> 4, h_ = bh & 15;
  const int q0 = blockIdx.x * 128;
  const unsigned short* Qp = Qh + ((size_t)bh * SEQ + q0) * HDIM;
  const unsigned short* Kp = Kh + (size_t)bh * SEQ * HDIM;
  const unsigned short* Vp = Vt + (size_t)bh * HDIM * SEQ;
  const int qw = wid * 32;

  // Q fragments (row/col = lane&15 -> q, k = hd = ks*32+g*8..)
  bf16x8 qf[2][2];
#pragma unroll
  for (int fr = 0; fr < 2; ++fr)
#pragma unroll
    for (int ks = 0; ks < 2; ++ks)
      qf[fr][ks] = *reinterpret_cast<const bf16x8*>(
          Qp + (size_t)(qw + fr * 16 + r16) * HDIM + ks * 32 + g * 8);

  // ones B-fragment: col 0 = 1.0 (bf16 0x3F80) -> D[:,0] = row sums of P
  bf16x8 vones;
#pragma unroll
  for (int i = 0; i < 8; ++i) vones[i] = (r16 == 0) ? (short)0x3F80 : (short)0;

  // staging source offsets (swizzled source chunks; LDS dest wave-linear)
  const int slot0 = wid * 64 + lane, slot1 = (4 + wid) * 64 + lane;
  const int sr0 = slot0 >> 3, sc0 = (slot0 & 7) ^ (sr0 & 7);
  const int sr1 = slot1 >> 3, sc1 = (slot1 & 7) ^ (sr1 & 7);
  const unsigned short* Ks0 = Kp + (size_t)sr0 * HDIM + sc0 * 8;
  const unsigned short* Ks1 = Kp + (size_t)sr1 * HDIM + sc1 * 8;
  const unsigned short* Vs0 = Vp + (size_t)sr0 * SEQ + sc0 * 8;
  const unsigned short* Vs1 = Vp + (size_t)sr1 * SEQ + sc1 * 8;
  const int ld0 = wid * 512, ld1 = (4 + wid) * 512;

  f32x4 o[2][4], ol[2];
#pragma unroll
  for (int fr = 0; fr < 2; ++fr) {
#pragma unroll
    for (int hf = 0; hf < 4; ++hf) o[fr][hf] = f32x4{0.f, 0.f, 0.f, 0.f};
    ol[fr] = f32x4{0.f, 0.f, 0.f, 0.f};
  }

  for (int t = 0; t < SEQ / 64; ++t) {
    __syncthreads();  // WAR: all waves done reading tile t-1 from Kl/Vl
    {
      const size_t koff = (size_t)t * 64 * HDIM;
      const int voff = t * 64;
      gload16(Ks0 + koff, &Kl[ld0]);
      gload16(Ks1 + koff, &Kl[ld1]);
      gload16(Vs0 + voff, &Vl[ld0]);
      gload16(Vs1 + voff, &Vl[ld1]);
    }
    __syncthreads();  // RAW: barrier drains vmcnt -> tile t visible to all waves

    // S^T = K Q^T: A = K rows kv, B = Q cols q -> D[kv][q]
    // lane holds S[kv = cf*16 + g*4 + reg][q = fr*16 + r16]
    f32x4 s_[2][4];
#pragma unroll
    for (int fr = 0; fr < 2; ++fr)
#pragma unroll
      for (int cf = 0; cf < 4; ++cf) s_[fr][cf] = f32x4{0.f, 0.f, 0.f, 0.f};
#pragma unroll
    for (int cf = 0; cf < 4; ++cf) {
      int krow = cf * 16 + r16;
#pragma unroll
      for (int ks = 0; ks < 2; ++ks) {
        bf16x8 kf = *reinterpret_cast<const bf16x8*>(
            &Kl[krow * 64 + (((ks * 4 + g) ^ (krow & 7)) << 3)]);
#pragma unroll
        for (int fr = 0; fr < 2; ++fr)
          s_[fr][cf] = __builtin_amdgcn_mfma_f32_16x16x32_bf16(kf, qf[fr][ks], s_[fr][cf], 0, 0, 0);
      }
    }

    // P = exp2(S); pack via v_cvt_pk_bf16_f32, 4 consecutive kv -> one b64 LDS write
#pragma unroll
    for (int fr = 0; fr < 2; ++fr) {
      int prow = qw + fr * 16 + r16;
      int base = prow * 64, swz = prow & 7;
#pragma unroll
      for (int cf = 0; cf < 4; ++cf) {
        float p0 = ex2(s_[fr][cf][0]);
        float p1 = ex2(s_[fr][cf][1]);
        float p2 = ex2(s_[fr][cf][2]);
        float p3 = ex2(s_[fr][cf][3]);
        unsigned w0 = cvtpk(p0, p1);
        unsigned w1 = cvtpk(p2, p3);
        int off = base + (((cf * 2 + (g >> 1)) ^ swz) << 3) + (g & 1) * 4;
        *reinterpret_cast<u32x2*>(&Pl[off]) = u32x2{w0, w1};
      }
    }
    // (no barrier: Pl rows wave-private; same-wave LDS RAW ordered by lgkmcnt)

    // O += P V ; l += P 1  (A = P rows q; B = V cols hd from Vt rows / ones col)
#pragma unroll
    for (int ks = 0; ks < 2; ++ks) {
      bf16x8 pf[2];
#pragma unroll
      for (int fr = 0; fr < 2; ++fr) {
        int prow = qw + fr * 16 + r16;
        pf[fr] = *reinterpret_cast<const bf16x8*>(
            &Pl[prow * 64 + (((ks * 4 + g) ^ (prow & 7)) << 3)]);
      }
#pragma unroll
      for (int hf = 0; hf < 4; ++hf) {
        int vrow = hf * 16 + r16;
        bf16x8 vf = *reinterpret_cast<const bf16x8*>(
            &Vl[vrow * 64 + (((ks * 4 + g) ^ (vrow & 7)) << 3)]);
#pragma unroll
        for (int fr = 0; fr < 2; ++fr)
          o[fr][hf] = __builtin_amdgcn_mfma_f32_16x16x32_bf16(pf[fr], vf, o[fr][hf], 0, 0, 0);
      }
#pragma unroll
      for (int fr = 0; fr < 2; ++fr)
        ol[fr] = __builtin_amdgcn_mfma_f32_16x16x32_bf16(pf[fr], vones, ol[fr], 0, 0, 0);
    }
  }

  // epilogue: l for row 4g+q lives in lane (g,0) reg q; sink adds 1. Write X.
#pragma unroll
  for (int fr = 0; fr < 2; ++fr) {
#pragma unroll
    for (int q = 0; q < 4; ++q) {
      float lsum = __shfl(ol[fr][q], lane & 48, 64);
      float inv = 1.0f / (1.0f + lsum);
      int row = q0 + qw + fr * 16 + g * 4 + q;
      unsigned short* xp = X + (size_t)(b_ * SEQ + row) * DIM + h_ * 64;
#pragma unroll
      for (int hf = 0; hf < 4; ++hf) xp[hf * 16 + r16] = f2b(o[fr][hf][q] * inv);
    }
  }
}

extern "C" void kernel_launch(void* const* d_in, const int* in_sizes, int n_in,
                              void* d_out, int out_size, void* d_ws, size_t ws_size,
                              hipStream_t stream) {
  const float* q  = (const float*)d_in[0];
  const float* k  = (const float*)d_in[1];
  const float* v  = (const float*)d_in[2];
  const float* Wq = (const float*)d_in[3];
  const float* bq = (const float*)d_in[4];
  const float* Wk = (const float*)d_in[5];
  const float* bk = (const float*)d_in[6];
  const float* Wv = (const float*)d_in[7];
  const float* bv = (const float*)d_in[8];
  const float* Wf = (const float*)d_in[9];
  const float* bf = (const float*)d_in[10];

  char* ws = (char*)d_ws;
  unsigned short* Abuf = (unsigned short*)ws;                              // 8192*1024 bf16 (also attn X)
  unsigned short* Wt   = (unsigned short*)(ws + (size_t)16777216);         // up to 1024*1024 bf16
  unsigned short* Qh   = (unsigned short*)(ws + (size_t)16777216 + 2097152);
  unsigned short* Kh   = Qh + (size_t)MROWS * DIM;
  unsigned short* Vtb  = Kh + (size_t)MROWS * DIM;

  dim3 cvtg(4096), b256(256);
  dim3 tb(32, 8);
  dim3 gemmg(64, 8);
  dim3 attng(16, 64);
  dim3 fing(64, 2);

  const int n8 = MROWS * DIM / 8;
  const float qscale = 0.125f * 1.44269504088896f;  // 1/sqrt(64) * log2(e): S in log2 units

  // Q path
  k_cvt<<<cvtg, b256, 0, stream>>>(q, Abuf, n8);
  k_tcvt<<<dim3(32, 32), tb, 0, stream>>>(Wq, Wt, DIM, DIM);
  k_gemm<0><<<gemmg, b256, 0, stream>>>(Abuf, Wt, bq, (void*)Qh, DIM, DIM, qscale);
  // K path
  k_cvt<<<cvtg, b256, 0, stream>>>(k, Abuf, n8);
  k_tcvt<<<dim3(32, 32), tb, 0, stream>>>(Wk, Wt, DIM, DIM);
  k_gemm<0><<<gemmg, b256, 0, stream>>>(Abuf, Wt, bk, (void*)Kh, DIM, DIM, 1.0f);
  // V path (stored transposed per head)
  k_cvt<<<cvtg, b256, 0, stream>>>(v, Abuf, n8);
  k_tcvt<<<dim3(32, 32), tb, 0, stream>>>(Wv, Wt, DIM, DIM);
  k_gemm<1><<<gemmg, b256, 0, stream>>>(Abuf, Wt, bv, (void*)Vtb, DIM, DIM, 1.0f);
  // attention -> X (reuse Abuf)
  k_attn<<<attng, b256, 0, stream>>>(Qh, Kh, Vtb, Abuf);
  // final projection -> f32 out
  k_tcvt<<<dim3(8, 32), tb, 0, stream>>>(Wf, Wt, DIM, DOUT);
  k_gemm<2><<<fing, b256, 0, stream>>>(Abuf, Wt, bf, d_out, DIM, DOUT, 1.0f);
}

// Round 15
// 204.014 us; speedup vs baseline: 1.7996x; 1.0626x over previous
//
#include <hip/hip_runtime.h>
#include <stdint.h>

#define DI __device__ __forceinline__

typedef __attribute__((ext_vector_type(8))) short bf16x8;
typedef __attribute__((ext_vector_type(4))) float f32x4;
typedef __attribute__((ext_vector_type(8))) unsigned short u16x8;
typedef __attribute__((ext_vector_type(2))) unsigned int u32x2;
typedef __attribute__((ext_vector_type(4))) unsigned int u32x4;

static constexpr int BATCH = 4, SEQ = 2048, DIM = 1024, NH = 16, HDIM = 64, DOUT = 256;
static constexpr int MROWS = BATCH * SEQ;  // 8192

DI unsigned short f2b(float f) {
  union { float f; unsigned u; } v; v.f = f;
  unsigned u = v.u + 0x7FFFu + ((v.u >> 16) & 1u);
  return (unsigned short)(u >> 16);
}

DI float ex2(float x) {  // 2^x, single v_exp_f32
#if __has_builtin(__builtin_amdgcn_exp2f)
  return __builtin_amdgcn_exp2f(x);
#else
  float r; asm("v_exp_f32 %0, %1" : "=v"(r) : "v"(x)); return r;
#endif
}

DI unsigned cvtpk(float lo, float hi) {  // packed bf16(lo) | bf16(hi)<<16, RNE
  unsigned r; asm("v_cvt_pk_bf16_f32 %0, %1, %2" : "=v"(r) : "v"(lo), "v"(hi)); return r;
}

typedef const __attribute__((address_space(1))) unsigned int* gp1;
typedef __attribute__((address_space(3))) unsigned int* lp3;
DI void gload16(const void* g, void* l) {
  __builtin_amdgcn_global_load_lds((gp1)g, (lp3)l, 16, 0, 0);
}

// ---------------- f32 [R][C] -> bf16 [C][R] transpose-convert ----------------
__global__ void k_tcvt(const float* __restrict__ s, unsigned short* __restrict__ d, int R, int C) {
  __shared__ float t[32][33];
  int c0 = blockIdx.x * 32, r0 = blockIdx.y * 32;
  int tx = threadIdx.x, ty = threadIdx.y;  // block (32,8)
#pragma unroll
  for (int j = 0; j < 32; j += 8)
    t[ty + j][tx] = s[(size_t)(r0 + ty + j) * C + c0 + tx];
  __syncthreads();
#pragma unroll
  for (int j = 0; j < 32; j += 8)
    d[(size_t)(c0 + ty + j) * R + r0 + tx] = f2b(t[tx][ty + j]);
}

// ---------------- bf16 GEMM: A[M,K] x Bt[N,K]^T, 128x128 tile, BK=32 ----------------
// AF32: A is f32 in global; staged to LDS bf16 via reg loads + v_cvt_pk_bf16_f32
//       (replaces the separate k_cvt pass; thread->LDS layout identical to the
//        gload16 path: slot = j*256+tid, elem off = row*32 + c8*8).
// MODE 0: out bf16 [B,H,S,HD]   (n = h*64+hd, m = b*2048+s), v = (acc+bias)*scale
// MODE 1: out bf16 [B,H,HD,S]   (V transposed per head)
// MODE 2: out f32  [M,N] row-major
template <int MODE, bool AF32>
__global__ __launch_bounds__(256, 2) void k_gemm(
    const void* __restrict__ Ain, const unsigned short* __restrict__ Bt,
    const float* __restrict__ bias, void* __restrict__ out, int K, int N, float scale) {
  __shared__ unsigned short Al[128 * 32];
  __shared__ unsigned short Bl[128 * 32];
  const int tid = threadIdx.x, wid = tid >> 6, lane = tid & 63;
  const int m0 = blockIdx.x * 128, n0 = blockIdx.y * 128;
  const int wr = wid >> 1, wc = wid & 1;
  const int g = lane >> 4, r16 = lane & 15;

  const float* Af = (const float*)Ain;
  const unsigned short* Ab = (const unsigned short*)Ain;

  // AF32 reg-staging geometry: slot f8 = j*256+tid -> row = f8>>2, col8 = (f8&3)*8
  const int ra = tid >> 2, ca = (tid & 3) * 8;
  const int rb = (256 + tid) >> 2, cb = ((256 + tid) & 3) * 8;
  float4 ar[2][2];
  if constexpr (AF32) {
    const float4* pa = reinterpret_cast<const float4*>(Af + (size_t)(m0 + ra) * K + ca);
    const float4* pb = reinterpret_cast<const float4*>(Af + (size_t)(m0 + rb) * K + cb);
    ar[0][0] = pa[0]; ar[0][1] = pa[1];
    ar[1][0] = pb[0]; ar[1][1] = pb[1];
  }

  f32x4 acc[4][4];
#pragma unroll
  for (int i = 0; i < 4; ++i)
#pragma unroll
    for (int j = 0; j < 4; ++j) acc[i][j] = f32x4{0.f, 0.f, 0.f, 0.f};

  for (int kk = 0; kk < K; kk += 32) {
    if constexpr (AF32) {
      // stage A from regs (prev iter's bottom barrier is the WAR point)
      u32x4 w0{cvtpk(ar[0][0].x, ar[0][0].y), cvtpk(ar[0][0].z, ar[0][0].w),
               cvtpk(ar[0][1].x, ar[0][1].y), cvtpk(ar[0][1].z, ar[0][1].w)};
      *reinterpret_cast<u32x4*>(&Al[ra * 32 + ca]) = w0;
      u32x4 w1{cvtpk(ar[1][0].x, ar[1][0].y), cvtpk(ar[1][0].z, ar[1][0].w),
               cvtpk(ar[1][1].x, ar[1][1].y), cvtpk(ar[1][1].z, ar[1][1].w)};
      *reinterpret_cast<u32x4*>(&Al[rb * 32 + cb]) = w1;
    } else {
#pragma unroll
      for (int is = 0; is < 2; ++is) {
        int slot = (is * 4 + wid) * 64 + lane;
        int row = slot >> 2, ch = slot & 3;
        gload16(Ab + (size_t)(m0 + row) * K + kk + ch * 8, &Al[(is * 4 + wid) * 64 * 8]);
      }
    }
#pragma unroll
    for (int is = 0; is < 2; ++is) {
      int slot = (is * 4 + wid) * 64 + lane;
      int row = slot >> 2, ch = slot & 3;
      gload16(Bt + (size_t)(n0 + row) * K + kk + ch * 8, &Bl[(is * 4 + wid) * 64 * 8]);
    }
    __syncthreads();  // RAW: A ds_writes (lgkm) + B gloads (vmcnt) visible
    if constexpr (AF32) {
      if (kk + 32 < K) {  // issue next A f32 loads AFTER the barrier (overlap MFMA)
        const float4* pa = reinterpret_cast<const float4*>(Af + (size_t)(m0 + ra) * K + kk + 32 + ca);
        const float4* pb = reinterpret_cast<const float4*>(Af + (size_t)(m0 + rb) * K + kk + 32 + cb);
        ar[0][0] = pa[0]; ar[0][1] = pa[1];
        ar[1][0] = pb[0]; ar[1][1] = pb[1];
      }
    }
    bf16x8 af[4], bfv[4];
#pragma unroll
    for (int i = 0; i < 4; ++i)
      af[i] = *reinterpret_cast<const bf16x8*>(&Al[(wr * 64 + i * 16 + r16) * 32 + g * 8]);
#pragma unroll
    for (int j = 0; j < 4; ++j)
      bfv[j] = *reinterpret_cast<const bf16x8*>(&Bl[(wc * 64 + j * 16 + r16) * 32 + g * 8]);
#pragma unroll
    for (int i = 0; i < 4; ++i)
#pragma unroll
      for (int j = 0; j < 4; ++j)
        acc[i][j] = __builtin_amdgcn_mfma_f32_16x16x32_bf16(af[i], bfv[j], acc[i][j], 0, 0, 0);
    __syncthreads();  // WAR: all reads done before next iter's staging writes
  }

  const int rr = g * 4;
#pragma unroll
  for (int i = 0; i < 4; ++i) {
#pragma unroll
    for (int j = 0; j < 4; ++j) {
#pragma unroll
      for (int q = 0; q < 4; ++q) {
        int mrow = m0 + wr * 64 + i * 16 + rr + q;
        int ncol = n0 + wc * 64 + j * 16 + r16;
        float v = (acc[i][j][q] + bias[ncol]) * scale;
        if (MODE == 0) {
          int b_ = mrow >> 11, s_ = mrow & 2047;
          int h_ = ncol >> 6, hd = ncol & 63;
          ((unsigned short*)out)[(((size_t)(b_ * NH + h_) * SEQ + s_) << 6) + hd] = f2b(v);
        } else if (MODE == 1) {
          int b_ = mrow >> 11, s_ = mrow & 2047;
          int h_ = ncol >> 6, hd = ncol & 63;
          ((unsigned short*)out)[(((size_t)(b_ * NH + h_) * HDIM + hd) << 11) + s_] = f2b(v);
        } else {
          ((float*)out)[(size_t)mrow * N + ncol] = v;
        }
      }
    }
  }
}

// ---------------- attention with "+1" sink softmax, NO max subtraction ----------------
// P = exp2(S) directly (reference computes exp(x)/(1+sum) without max-sub; logits
// bounded). Row sums ride the matrix pipe via a ones-column B-fragment.
// SWAPPED QK^T: s = mfma(K_frag, Q_frag) -> D[kv][q]; lane holds 4 consecutive kv
// per q-row. P store: 16x v_cvt_pk_bf16_f32 + 8x ds_write_b64 per tile.
// Single-buffered K/V: 32KB LDS, __launch_bounds__(256,4) (r9: (256,5) spilled).
__global__ __launch_bounds__(256, 4) void k_attn(
    const unsigned short* __restrict__ Qh, const unsigned short* __restrict__ Kh,
    const unsigned short* __restrict__ Vt, unsigned short* __restrict__ X) {
  __shared__ unsigned short Kl[64 * 64];   // [kv][hd], chunk-swizzled
  __shared__ unsigned short Vl[64 * 64];   // [hd][kv], chunk-swizzled
  __shared__ unsigned short Pl[128 * 64];  // [q][kv],  chunk-swizzled (wave-private rows)

  const int tid = threadIdx.x, wid = tid >> 6, lane = tid & 63;
  const int g = lane >> 4, r16 = lane & 15;
  const int bh = blockIdx.y, b_ = bh >> 4, h_ = bh & 15;
  const int q0 = blockIdx.x * 128;
  const unsigned short* Qp = Qh + ((size_t)bh * SEQ + q0) * HDIM;
  const unsigned short* Kp = Kh + (size_t)bh * SEQ * HDIM;
  const unsigned short* Vp = Vt + (size_t)bh * HDIM * SEQ;
  const int qw = wid * 32;

  // Q fragments (row/col = lane&15 -> q, k = hd = ks*32+g*8..)
  bf16x8 qf[2][2];
#pragma unroll
  for (int fr = 0; fr < 2; ++fr)
#pragma unroll
    for (int ks = 0; ks < 2; ++ks)
      qf[fr][ks] = *reinterpret_cast<const bf16x8*>(
          Qp + (size_t)(qw + fr * 16 + r16) * HDIM + ks * 32 + g * 8);

  // ones B-fragment: col 0 = 1.0 (bf16 0x3F80) -> D[:,0] = row sums of P
  bf16x8 vones;
#pragma unroll
  for (int i = 0; i < 8; ++i) vones[i] = (r16 == 0) ? (short)0x3F80 : (short)0;

  // staging source offsets (swizzled source chunks; LDS dest wave-linear)
  const int slot0 = wid * 64 + lane, slot1 = (4 + wid) * 64 + lane;
  const int sr0 = slot0 >> 3, sc0 = (slot0 & 7) ^ (sr0 & 7);
  const int sr1 = slot1 >> 3, sc1 = (slot1 & 7) ^ (sr1 & 7);
  const unsigned short* Ks0 = Kp + (size_t)sr0 * HDIM + sc0 * 8;
  const unsigned short* Ks1 = Kp + (size_t)sr1 * HDIM + sc1 * 8;
  const unsigned short* Vs0 = Vp + (size_t)sr0 * SEQ + sc0 * 8;
  const unsigned short* Vs1 = Vp + (size_t)sr1 * SEQ + sc1 * 8;
  const int ld0 = wid * 512, ld1 = (4 + wid) * 512;

  f32x4 o[2][4], ol[2];
#pragma unroll
  for (int fr = 0; fr < 2; ++fr) {
#pragma unroll
    for (int hf = 0; hf < 4; ++hf) o[fr][hf] = f32x4{0.f, 0.f, 0.f, 0.f};
    ol[fr] = f32x4{0.f, 0.f, 0.f, 0.f};
  }

  for (int t = 0; t < SEQ / 64; ++t) {
    __syncthreads();  // WAR: all waves done reading tile t-1 from Kl/Vl
    {
      const size_t koff = (size_t)t * 64 * HDIM;
      const int voff = t * 64;
      gload16(Ks0 + koff, &Kl[ld0]);
      gload16(Ks1 + koff, &Kl[ld1]);
      gload16(Vs0 + voff, &Vl[ld0]);
      gload16(Vs1 + voff, &Vl[ld1]);
    }
    __syncthreads();  // RAW: barrier drains vmcnt -> tile t visible to all waves

    // S^T = K Q^T: A = K rows kv, B = Q cols q -> D[kv][q]
    f32x4 s_[2][4];
#pragma unroll
    for (int fr = 0; fr < 2; ++fr)
#pragma unroll
      for (int cf = 0; cf < 4; ++cf) s_[fr][cf] = f32x4{0.f, 0.f, 0.f, 0.f};
#pragma unroll
    for (int cf = 0; cf < 4; ++cf) {
      int krow = cf * 16 + r16;
#pragma unroll
      for (int ks = 0; ks < 2; ++ks) {
        bf16x8 kf = *reinterpret_cast<const bf16x8*>(
            &Kl[krow * 64 + (((ks * 4 + g) ^ (krow & 7)) << 3)]);
#pragma unroll
        for (int fr = 0; fr < 2; ++fr)
          s_[fr][cf] = __builtin_amdgcn_mfma_f32_16x16x32_bf16(kf, qf[fr][ks], s_[fr][cf], 0, 0, 0);
      }
    }

    // P = exp2(S); pack via v_cvt_pk_bf16_f32, 4 consecutive kv -> one b64 LDS write
#pragma unroll
    for (int fr = 0; fr < 2; ++fr) {
      int prow = qw + fr * 16 + r16;
      int base = prow * 64, swz = prow & 7;
#pragma unroll
      for (int cf = 0; cf < 4; ++cf) {
        float p0 = ex2(s_[fr][cf][0]);
        float p1 = ex2(s_[fr][cf][1]);
        float p2 = ex2(s_[fr][cf][2]);
        float p3 = ex2(s_[fr][cf][3]);
        unsigned w0 = cvtpk(p0, p1);
        unsigned w1 = cvtpk(p2, p3);
        int off = base + (((cf * 2 + (g >> 1)) ^ swz) << 3) + (g & 1) * 4;
        *reinterpret_cast<u32x2*>(&Pl[off]) = u32x2{w0, w1};
      }
    }
    // (no barrier: Pl rows wave-private; same-wave LDS RAW ordered by lgkmcnt)

    // O += P V ; l += P 1  (A = P rows q; B = V cols hd from Vt rows / ones col)
#pragma unroll
    for (int ks = 0; ks < 2; ++ks) {
      bf16x8 pf[2];
#pragma unroll
      for (int fr = 0; fr < 2; ++fr) {
        int prow = qw + fr * 16 + r16;
        pf[fr] = *reinterpret_cast<const bf16x8*>(
            &Pl[prow * 64 + (((ks * 4 + g) ^ (prow & 7)) << 3)]);
      }
#pragma unroll
      for (int hf = 0; hf < 4; ++hf) {
        int vrow = hf * 16 + r16;
        bf16x8 vf = *reinterpret_cast<const bf16x8*>(
            &Vl[vrow * 64 + (((ks * 4 + g) ^ (vrow & 7)) << 3)]);
#pragma unroll
        for (int fr = 0; fr < 2; ++fr)
          o[fr][hf] = __builtin_amdgcn_mfma_f32_16x16x32_bf16(pf[fr], vf, o[fr][hf], 0, 0, 0);
      }
#pragma unroll
      for (int fr = 0; fr < 2; ++fr)
        ol[fr] = __builtin_amdgcn_mfma_f32_16x16x32_bf16(pf[fr], vones, ol[fr], 0, 0, 0);
    }
  }

  // epilogue: l for row 4g+q lives in lane (g,0) reg q; sink adds 1. Write X.
#pragma unroll
  for (int fr = 0; fr < 2; ++fr) {
#pragma unroll
    for (int q = 0; q < 4; ++q) {
      float lsum = __shfl(ol[fr][q], lane & 48, 64);
      float inv = 1.0f / (1.0f + lsum);
      int row = q0 + qw + fr * 16 + g * 4 + q;
      unsigned short* xp = X + (size_t)(b_ * SEQ + row) * DIM + h_ * 64;
#pragma unroll
      for (int hf = 0; hf < 4; ++hf) xp[hf * 16 + r16] = f2b(o[fr][hf][q] * inv);
    }
  }
}

extern "C" void kernel_launch(void* const* d_in, const int* in_sizes, int n_in,
                              void* d_out, int out_size, void* d_ws, size_t ws_size,
                              hipStream_t stream) {
  const float* q  = (const float*)d_in[0];
  const float* k  = (const float*)d_in[1];
  const float* v  = (const float*)d_in[2];
  const float* Wq = (const float*)d_in[3];
  const float* bq = (const float*)d_in[4];
  const float* Wk = (const float*)d_in[5];
  const float* bk = (const float*)d_in[6];
  const float* Wv = (const float*)d_in[7];
  const float* bv = (const float*)d_in[8];
  const float* Wf = (const float*)d_in[9];
  const float* bf = (const float*)d_in[10];

  char* ws = (char*)d_ws;
  unsigned short* Abuf = (unsigned short*)ws;                              // attn X (8192*1024 bf16)
  unsigned short* Wt   = (unsigned short*)(ws + (size_t)16777216);         // up to 1024*1024 bf16
  unsigned short* Qh   = (unsigned short*)(ws + (size_t)16777216 + 2097152);
  unsigned short* Kh   = Qh + (size_t)MROWS * DIM;
  unsigned short* Vtb  = Kh + (size_t)MROWS * DIM;

  dim3 b256(256);
  dim3 tb(32, 8);
  dim3 gemmg(64, 8);
  dim3 attng(16, 64);
  dim3 fing(64, 2);

  const float qscale = 0.125f * 1.44269504088896f;  // 1/sqrt(64) * log2(e): S in log2 units

  // Q path (f32 A staged in-GEMM; no separate convert pass)
  k_tcvt<<<dim3(32, 32), tb, 0, stream>>>(Wq, Wt, DIM, DIM);
  k_gemm<0, true><<<gemmg, b256, 0, stream>>>(q, Wt, bq, (void*)Qh, DIM, DIM, qscale);
  // K path
  k_tcvt<<<dim3(32, 32), tb, 0, stream>>>(Wk, Wt, DIM, DIM);
  k_gemm<0, true><<<gemmg, b256, 0, stream>>>(k, Wt, bk, (void*)Kh, DIM, DIM, 1.0f);
  // V path (stored transposed per head)
  k_tcvt<<<dim3(32, 32), tb, 0, stream>>>(Wv, Wt, DIM, DIM);
  k_gemm<1, true><<<gemmg, b256, 0, stream>>>(v, Wt, bv, (void*)Vtb, DIM, DIM, 1.0f);
  // attention -> X (Abuf)
  k_attn<<<attng, b256, 0, stream>>>(Qh, Kh, Vtb, Abuf);
  // final projection -> f32 out
  k_tcvt<<<dim3(8, 32), tb, 0, stream>>>(Wf, Wt, DIM, DOUT);
  k_gemm<2, false><<<fing, b256, 0, stream>>>(Abuf, Wt, bf, d_out, DIM, DOUT, 1.0f);
}

// Round 17
// 189.866 us; speedup vs baseline: 1.9337x; 1.0745x over previous
//
#include <hip/hip_runtime.h>
#include <stdint.h>

#define DI __device__ __forceinline__

typedef __attribute__((ext_vector_type(8))) short bf16x8;
typedef __attribute__((ext_vector_type(4))) float f32x4;
typedef __attribute__((ext_vector_type(8))) unsigned short u16x8;
typedef __attribute__((ext_vector_type(2))) unsigned int u32x2;
typedef __attribute__((ext_vector_type(4))) unsigned int u32x4;

static constexpr int BATCH = 4, SEQ = 2048, DIM = 1024, NH = 16, HDIM = 64, DOUT = 256;
static constexpr int MROWS = BATCH * SEQ;  // 8192

DI unsigned short f2b(float f) {
  union { float f; unsigned u; } v; v.f = f;
  unsigned u = v.u + 0x7FFFu + ((v.u >> 16) & 1u);
  return (unsigned short)(u >> 16);
}

DI float ex2(float x) {  // 2^x, single v_exp_f32
#if __has_builtin(__builtin_amdgcn_exp2f)
  return __builtin_amdgcn_exp2f(x);
#else
  float r; asm("v_exp_f32 %0, %1" : "=v"(r) : "v"(x)); return r;
#endif
}

DI unsigned cvtpk(float lo, float hi) {  // packed bf16(lo) | bf16(hi)<<16, RNE
  unsigned r; asm("v_cvt_pk_bf16_f32 %0, %1, %2" : "=v"(r) : "v"(lo), "v"(hi)); return r;
}

typedef const __attribute__((address_space(1))) unsigned int* gp1;
typedef __attribute__((address_space(3))) unsigned int* lp3;
DI void gload16(const void* g, void* l) {
  __builtin_amdgcn_global_load_lds((gp1)g, (lp3)l, 16, 0, 0);
}

// ---------------- f32 [R][C] -> bf16 [C][R] transpose-convert (z-batched) ----------------
__global__ void k_tcvt3(const float* __restrict__ s0, const float* __restrict__ s1,
                        const float* __restrict__ s2, unsigned short* __restrict__ d, int R, int C) {
  __shared__ float t[32][33];
  const float* s = (blockIdx.z == 0) ? s0 : (blockIdx.z == 1) ? s1 : s2;
  unsigned short* dz = d + (size_t)blockIdx.z * R * C;
  int c0 = blockIdx.x * 32, r0 = blockIdx.y * 32;
  int tx = threadIdx.x, ty = threadIdx.y;  // block (32,8)
#pragma unroll
  for (int j = 0; j < 32; j += 8)
    t[ty + j][tx] = s[(size_t)(r0 + ty + j) * C + c0 + tx];
  __syncthreads();
#pragma unroll
  for (int j = 0; j < 32; j += 8)
    dz[(size_t)(c0 + ty + j) * R + r0 + tx] = f2b(t[tx][ty + j]);
}

__global__ void k_tcvt(const float* __restrict__ s, unsigned short* __restrict__ d, int R, int C) {
  __shared__ float t[32][33];
  int c0 = blockIdx.x * 32, r0 = blockIdx.y * 32;
  int tx = threadIdx.x, ty = threadIdx.y;  // block (32,8)
#pragma unroll
  for (int j = 0; j < 32; j += 8)
    t[ty + j][tx] = s[(size_t)(r0 + ty + j) * C + c0 + tx];
  __syncthreads();
#pragma unroll
  for (int j = 0; j < 32; j += 8)
    d[(size_t)(c0 + ty + j) * R + r0 + tx] = f2b(t[tx][ty + j]);
}

// ---------------- fused QKV projection: 3 GEMMs in one launch (z = 0:Q 1:K 2:V) ----------
// A f32 [8192,1024] staged to LDS bf16 via reg loads + cvt_pk (r15-verified path).
// z=0: out Qh bf16 [B,H,S,HD], scale=qscale; z=1: out Kh same layout, scale=1;
// z=2: out Vtb bf16 [B,H,HD,S] (transposed per head), scale=1.
__global__ __launch_bounds__(256, 2) void k_gemm3(
    const float* __restrict__ Aq, const float* __restrict__ Ak, const float* __restrict__ Av,
    const unsigned short* __restrict__ Wt3,
    const float* __restrict__ bq, const float* __restrict__ bk, const float* __restrict__ bv,
    unsigned short* __restrict__ Qh, unsigned short* __restrict__ Kh,
    unsigned short* __restrict__ Vtb, float qscale) {
  __shared__ unsigned short Al[128 * 32];
  __shared__ unsigned short Bl[128 * 32];
  const int tid = threadIdx.x, wid = tid >> 6, lane = tid & 63;
  const int m0 = blockIdx.x * 128, n0 = blockIdx.y * 128;
  const int z = blockIdx.z;
  const int wr = wid >> 1, wc = wid & 1;
  const int g = lane >> 4, r16 = lane & 15;
  const int K = DIM;

  const float* Af = (z == 0) ? Aq : (z == 1) ? Ak : Av;
  const unsigned short* Bt = Wt3 + (size_t)z * DIM * DIM;
  const float* bias = (z == 0) ? bq : (z == 1) ? bk : bv;
  const float scale = (z == 0) ? qscale : 1.0f;

  // reg-staging geometry: slot f8 = j*256+tid -> row = f8>>2, col8 = (f8&3)*8
  const int ra = tid >> 2, ca = (tid & 3) * 8;
  const int rb = (256 + tid) >> 2, cb = ((256 + tid) & 3) * 8;
  float4 ar[2][2];
  {
    const float4* pa = reinterpret_cast<const float4*>(Af + (size_t)(m0 + ra) * K + ca);
    const float4* pb = reinterpret_cast<const float4*>(Af + (size_t)(m0 + rb) * K + cb);
    ar[0][0] = pa[0]; ar[0][1] = pa[1];
    ar[1][0] = pb[0]; ar[1][1] = pb[1];
  }

  f32x4 acc[4][4];
#pragma unroll
  for (int i = 0; i < 4; ++i)
#pragma unroll
    for (int j = 0; j < 4; ++j) acc[i][j] = f32x4{0.f, 0.f, 0.f, 0.f};

  for (int kk = 0; kk < K; kk += 32) {
    // stage A from regs (prev iter's bottom barrier is the WAR point)
    u32x4 w0{cvtpk(ar[0][0].x, ar[0][0].y), cvtpk(ar[0][0].z, ar[0][0].w),
             cvtpk(ar[0][1].x, ar[0][1].y), cvtpk(ar[0][1].z, ar[0][1].w)};
    *reinterpret_cast<u32x4*>(&Al[ra * 32 + ca]) = w0;
    u32x4 w1{cvtpk(ar[1][0].x, ar[1][0].y), cvtpk(ar[1][0].z, ar[1][0].w),
             cvtpk(ar[1][1].x, ar[1][1].y), cvtpk(ar[1][1].z, ar[1][1].w)};
    *reinterpret_cast<u32x4*>(&Al[rb * 32 + cb]) = w1;
#pragma unroll
    for (int is = 0; is < 2; ++is) {
      int slot = (is * 4 + wid) * 64 + lane;
      int row = slot >> 2, ch = slot & 3;
      gload16(Bt + (size_t)(n0 + row) * K + kk + ch * 8, &Bl[(is * 4 + wid) * 64 * 8]);
    }
    __syncthreads();  // RAW: A ds_writes (lgkm) + B gloads (vmcnt) visible
    if (kk + 32 < K) {  // issue next A f32 loads AFTER the barrier (overlap MFMA)
      const float4* pa = reinterpret_cast<const float4*>(Af + (size_t)(m0 + ra) * K + kk + 32 + ca);
      const float4* pb = reinterpret_cast<const float4*>(Af + (size_t)(m0 + rb) * K + kk + 32 + cb);
      ar[0][0] = pa[0]; ar[0][1] = pa[1];
      ar[1][0] = pb[0]; ar[1][1] = pb[1];
    }
    bf16x8 af[4], bfv[4];
#pragma unroll
    for (int i = 0; i < 4; ++i)
      af[i] = *reinterpret_cast<const bf16x8*>(&Al[(wr * 64 + i * 16 + r16) * 32 + g * 8]);
#pragma unroll
    for (int j = 0; j < 4; ++j)
      bfv[j] = *reinterpret_cast<const bf16x8*>(&Bl[(wc * 64 + j * 16 + r16) * 32 + g * 8]);
#pragma unroll
    for (int i = 0; i < 4; ++i)
#pragma unroll
      for (int j = 0; j < 4; ++j)
        acc[i][j] = __builtin_amdgcn_mfma_f32_16x16x32_bf16(af[i], bfv[j], acc[i][j], 0, 0, 0);
    __syncthreads();  // WAR: all reads done before next iter's staging writes
  }

  const int rr = g * 4;
#pragma unroll
  for (int i = 0; i < 4; ++i) {
#pragma unroll
    for (int j = 0; j < 4; ++j) {
#pragma unroll
      for (int q = 0; q < 4; ++q) {
        int mrow = m0 + wr * 64 + i * 16 + rr + q;
        int ncol = n0 + wc * 64 + j * 16 + r16;
        float v = (acc[i][j][q] + bias[ncol]) * scale;
        int b_ = mrow >> 11, s_ = mrow & 2047;
        int h_ = ncol >> 6, hd = ncol & 63;
        if (z == 2) {
          Vtb[(((size_t)(b_ * NH + h_) * HDIM + hd) << 11) + s_] = f2b(v);
        } else {
          unsigned short* dst = (z == 0) ? Qh : Kh;
          dst[(((size_t)(b_ * NH + h_) * SEQ + s_) << 6) + hd] = f2b(v);
        }
      }
    }
  }
}

// ---------------- final projection: A bf16 [M,K] x Wt [N,K]^T -> f32 [M,N] ----------------
__global__ __launch_bounds__(256, 2) void k_gemmf(
    const unsigned short* __restrict__ A, const unsigned short* __restrict__ Bt,
    const float* __restrict__ bias, float* __restrict__ out, int K, int N) {
  __shared__ unsigned short Al[128 * 32];
  __shared__ unsigned short Bl[128 * 32];
  const int tid = threadIdx.x, wid = tid >> 6, lane = tid & 63;
  const int m0 = blockIdx.x * 128, n0 = blockIdx.y * 128;
  const int wr = wid >> 1, wc = wid & 1;
  const int g = lane >> 4, r16 = lane & 15;

  f32x4 acc[4][4];
#pragma unroll
  for (int i = 0; i < 4; ++i)
#pragma unroll
    for (int j = 0; j < 4; ++j) acc[i][j] = f32x4{0.f, 0.f, 0.f, 0.f};

  for (int kk = 0; kk < K; kk += 32) {
#pragma unroll
    for (int is = 0; is < 2; ++is) {
      int slot = (is * 4 + wid) * 64 + lane;
      int row = slot >> 2, ch = slot & 3;
      gload16(A + (size_t)(m0 + row) * K + kk + ch * 8, &Al[(is * 4 + wid) * 64 * 8]);
    }
#pragma unroll
    for (int is = 0; is < 2; ++is) {
      int slot = (is * 4 + wid) * 64 + lane;
      int row = slot >> 2, ch = slot & 3;
      gload16(Bt + (size_t)(n0 + row) * K + kk + ch * 8, &Bl[(is * 4 + wid) * 64 * 8]);
    }
    __syncthreads();
    bf16x8 af[4], bfv[4];
#pragma unroll
    for (int i = 0; i < 4; ++i)
      af[i] = *reinterpret_cast<const bf16x8*>(&Al[(wr * 64 + i * 16 + r16) * 32 + g * 8]);
#pragma unroll
    for (int j = 0; j < 4; ++j)
      bfv[j] = *reinterpret_cast<const bf16x8*>(&Bl[(wc * 64 + j * 16 + r16) * 32 + g * 8]);
#pragma unroll
    for (int i = 0; i < 4; ++i)
#pragma unroll
      for (int j = 0; j < 4; ++j)
        acc[i][j] = __builtin_amdgcn_mfma_f32_16x16x32_bf16(af[i], bfv[j], acc[i][j], 0, 0, 0);
    __syncthreads();
  }

  const int rr = g * 4;
#pragma unroll
  for (int i = 0; i < 4; ++i)
#pragma unroll
    for (int j = 0; j < 4; ++j)
#pragma unroll
      for (int q = 0; q < 4; ++q) {
        int mrow = m0 + wr * 64 + i * 16 + rr + q;
        int ncol = n0 + wc * 64 + j * 16 + r16;
        out[(size_t)mrow * N + ncol] = acc[i][j][q] + bias[ncol];
      }
}

// ---------------- attention with "+1" sink softmax, NO max subtraction ----------------
// (r14-verified: swapped QK^T, exp2 domain, cvt_pk P-pack, ones-column row sums,
//  single-buffer 32KB LDS, launch_bounds(256,4))
__global__ __launch_bounds__(256, 4) void k_attn(
    const unsigned short* __restrict__ Qh, const unsigned short* __restrict__ Kh,
    const unsigned short* __restrict__ Vt, unsigned short* __restrict__ X) {
  __shared__ unsigned short Kl[64 * 64];   // [kv][hd], chunk-swizzled
  __shared__ unsigned short Vl[64 * 64];   // [hd][kv], chunk-swizzled
  __shared__ unsigned short Pl[128 * 64];  // [q][kv],  chunk-swizzled (wave-private rows)

  const int tid = threadIdx.x, wid = tid >> 6, lane = tid & 63;
  const int g = lane >> 4, r16 = lane & 15;
  const int bh = blockIdx.y, b_ = bh >> 4, h_ = bh & 15;
  const int q0 = blockIdx.x * 128;
  const unsigned short* Qp = Qh + ((size_t)bh * SEQ + q0) * HDIM;
  const unsigned short* Kp = Kh + (size_t)bh * SEQ * HDIM;
  const unsigned short* Vp = Vt + (size_t)bh * HDIM * SEQ;
  const int qw = wid * 32;

  bf16x8 qf[2][2];
#pragma unroll
  for (int fr = 0; fr < 2; ++fr)
#pragma unroll
    for (int ks = 0; ks < 2; ++ks)
      qf[fr][ks] = *reinterpret_cast<const bf16x8*>(
          Qp + (size_t)(qw + fr * 16 + r16) * HDIM + ks * 32 + g * 8);

  bf16x8 vones;
#pragma unroll
  for (int i = 0; i < 8; ++i) vones[i] = (r16 == 0) ? (short)0x3F80 : (short)0;

  const int slot0 = wid * 64 + lane, slot1 = (4 + wid) * 64 + lane;
  const int sr0 = slot0 >> 3, sc0 = (slot0 & 7) ^ (sr0 & 7);
  const int sr1 = slot1 >> 3, sc1 = (slot1 & 7) ^ (sr1 & 7);
  const unsigned short* Ks0 = Kp + (size_t)sr0 * HDIM + sc0 * 8;
  const unsigned short* Ks1 = Kp + (size_t)sr1 * HDIM + sc1 * 8;
  const unsigned short* Vs0 = Vp + (size_t)sr0 * SEQ + sc0 * 8;
  const unsigned short* Vs1 = Vp + (size_t)sr1 * SEQ + sc1 * 8;
  const int ld0 = wid * 512, ld1 = (4 + wid) * 512;

  f32x4 o[2][4], ol[2];
#pragma unroll
  for (int fr = 0; fr < 2; ++fr) {
#pragma unroll
    for (int hf = 0; hf < 4; ++hf) o[fr][hf] = f32x4{0.f, 0.f, 0.f, 0.f};
    ol[fr] = f32x4{0.f, 0.f, 0.f, 0.f};
  }

  for (int t = 0; t < SEQ / 64; ++t) {
    __syncthreads();  // WAR
    {
      const size_t koff = (size_t)t * 64 * HDIM;
      const int voff = t * 64;
      gload16(Ks0 + koff, &Kl[ld0]);
      gload16(Ks1 + koff, &Kl[ld1]);
      gload16(Vs0 + voff, &Vl[ld0]);
      gload16(Vs1 + voff, &Vl[ld1]);
    }
    __syncthreads();  // RAW

    f32x4 s_[2][4];
#pragma unroll
    for (int fr = 0; fr < 2; ++fr)
#pragma unroll
      for (int cf = 0; cf < 4; ++cf) s_[fr][cf] = f32x4{0.f, 0.f, 0.f, 0.f};
#pragma unroll
    for (int cf = 0; cf < 4; ++cf) {
      int krow = cf * 16 + r16;
#pragma unroll
      for (int ks = 0; ks < 2; ++ks) {
        bf16x8 kf = *reinterpret_cast<const bf16x8*>(
            &Kl[krow * 64 + (((ks * 4 + g) ^ (krow & 7)) << 3)]);
#pragma unroll
        for (int fr = 0; fr < 2; ++fr)
          s_[fr][cf] = __builtin_amdgcn_mfma_f32_16x16x32_bf16(kf, qf[fr][ks], s_[fr][cf], 0, 0, 0);
      }
    }

#pragma unroll
    for (int fr = 0; fr < 2; ++fr) {
      int prow = qw + fr * 16 + r16;
      int base = prow * 64, swz = prow & 7;
#pragma unroll
      for (int cf = 0; cf < 4; ++cf) {
        float p0 = ex2(s_[fr][cf][0]);
        float p1 = ex2(s_[fr][cf][1]);
        float p2 = ex2(s_[fr][cf][2]);
        float p3 = ex2(s_[fr][cf][3]);
        unsigned w0 = cvtpk(p0, p1);
        unsigned w1 = cvtpk(p2, p3);
        int off = base + (((cf * 2 + (g >> 1)) ^ swz) << 3) + (g & 1) * 4;
        *reinterpret_cast<u32x2*>(&Pl[off]) = u32x2{w0, w1};
      }
    }

#pragma unroll
    for (int ks = 0; ks < 2; ++ks) {
      bf16x8 pf[2];
#pragma unroll
      for (int fr = 0; fr < 2; ++fr) {
        int prow = qw + fr * 16 + r16;
        pf[fr] = *reinterpret_cast<const bf16x8*>(
            &Pl[prow * 64 + (((ks * 4 + g) ^ (prow & 7)) << 3)]);
      }
#pragma unroll
      for (int hf = 0; hf < 4; ++hf) {
        int vrow = hf * 16 + r16;
        bf16x8 vf = *reinterpret_cast<const bf16x8*>(
            &Vl[vrow * 64 + (((ks * 4 + g) ^ (vrow & 7)) << 3)]);
#pragma unroll
        for (int fr = 0; fr < 2; ++fr)
          o[fr][hf] = __builtin_amdgcn_mfma_f32_16x16x32_bf16(pf[fr], vf, o[fr][hf], 0, 0, 0);
      }
#pragma unroll
      for (int fr = 0; fr < 2; ++fr)
        ol[fr] = __builtin_amdgcn_mfma_f32_16x16x32_bf16(pf[fr], vones, ol[fr], 0, 0, 0);
    }
  }

#pragma unroll
  for (int fr = 0; fr < 2; ++fr) {
#pragma unroll
    for (int q = 0; q < 4; ++q) {
      float lsum = __shfl(ol[fr][q], lane & 48, 64);
      float inv = 1.0f / (1.0f + lsum);
      int row = q0 + qw + fr * 16 + g * 4 + q;
      unsigned short* xp = X + (size_t)(b_ * SEQ + row) * DIM + h_ * 64;
#pragma unroll
      for (int hf = 0; hf < 4; ++hf) xp[hf * 16 + r16] = f2b(o[fr][hf][q] * inv);
    }
  }
}

extern "C" void kernel_launch(void* const* d_in, const int* in_sizes, int n_in,
                              void* d_out, int out_size, void* d_ws, size_t ws_size,
                              hipStream_t stream) {
  const float* q  = (const float*)d_in[0];
  const float* k  = (const float*)d_in[1];
  const float* v  = (const float*)d_in[2];
  const float* Wq = (const float*)d_in[3];
  const float* bq = (const float*)d_in[4];
  const float* Wk = (const float*)d_in[5];
  const float* bk = (const float*)d_in[6];
  const float* Wv = (const float*)d_in[7];
  const float* bv = (const float*)d_in[8];
  const float* Wf = (const float*)d_in[9];
  const float* bf = (const float*)d_in[10];

  char* ws = (char*)d_ws;
  unsigned short* Abuf = (unsigned short*)ws;                              // attn X (8192*1024 bf16)
  unsigned short* Wt3  = (unsigned short*)(ws + (size_t)16777216);         // 3 x 1024x1024 bf16
  unsigned short* Wtf  = Wt3 + (size_t)3 * DIM * DIM;                      // 256x1024 bf16
  unsigned short* Qh   = Wtf + (size_t)DOUT * DIM;
  unsigned short* Kh   = Qh + (size_t)MROWS * DIM;
  unsigned short* Vtb  = Kh + (size_t)MROWS * DIM;

  dim3 b256(256);
  dim3 tb(32, 8);

  const float qscale = 0.125f * 1.44269504088896f;  // 1/sqrt(64) * log2(e): S in log2 units

  // weights: 3 transposes in one launch; final-proj transpose separate
  k_tcvt3<<<dim3(32, 32, 3), tb, 0, stream>>>(Wq, Wk, Wv, Wt3, DIM, DIM);
  k_tcvt<<<dim3(8, 32), tb, 0, stream>>>(Wf, Wtf, DIM, DOUT);
  // fused QKV projection (1536 blocks, ~6/CU: cross-GEMM overlap)
  k_gemm3<<<dim3(64, 8, 3), b256, 0, stream>>>(q, k, v, Wt3, bq, bk, bv, Qh, Kh, Vtb, qscale);
  // attention -> X (Abuf)
  k_attn<<<dim3(16, 64), b256, 0, stream>>>(Qh, Kh, Vtb, Abuf);
  // final projection -> f32 out
  k_gemmf<<<dim3(64, 2), b256, 0, stream>>>(Abuf, Wtf, bf, (float*)d_out, DIM, DOUT);
}

// Round 18
// 189.541 us; speedup vs baseline: 1.9370x; 1.0017x over previous
//
#include <hip/hip_runtime.h>
#include <stdint.h>

#define DI __device__ __forceinline__

typedef __attribute__((ext_vector_type(8))) short bf16x8;
typedef __attribute__((ext_vector_type(4))) float f32x4;
typedef __attribute__((ext_vector_type(8))) unsigned short u16x8;
typedef __attribute__((ext_vector_type(2))) unsigned int u32x2;
typedef __attribute__((ext_vector_type(4))) unsigned int u32x4;

static constexpr int BATCH = 4, SEQ = 2048, DIM = 1024, NH = 16, HDIM = 64, DOUT = 256;
static constexpr int MROWS = BATCH * SEQ;  // 8192

DI unsigned short f2b(float f) {
  union { float f; unsigned u; } v; v.f = f;
  unsigned u = v.u + 0x7FFFu + ((v.u >> 16) & 1u);
  return (unsigned short)(u >> 16);
}

DI float ex2(float x) {  // 2^x, single v_exp_f32
#if __has_builtin(__builtin_amdgcn_exp2f)
  return __builtin_amdgcn_exp2f(x);
#else
  float r; asm("v_exp_f32 %0, %1" : "=v"(r) : "v"(x)); return r;
#endif
}

DI unsigned cvtpk(float lo, float hi) {  // packed bf16(lo) | bf16(hi)<<16, RNE
  unsigned r; asm("v_cvt_pk_bf16_f32 %0, %1, %2" : "=v"(r) : "v"(lo), "v"(hi)); return r;
}

typedef const __attribute__((address_space(1))) unsigned int* gp1;
typedef __attribute__((address_space(3))) unsigned int* lp3;
DI void gload16(const void* g, void* l) {
  __builtin_amdgcn_global_load_lds((gp1)g, (lp3)l, 16, 0, 0);
}

// ---------------- f32 [R][C] -> bf16 [C][R] transpose-convert (z-batched) ----------------
__global__ void k_tcvt3(const float* __restrict__ s0, const float* __restrict__ s1,
                        const float* __restrict__ s2, unsigned short* __restrict__ d, int R, int C) {
  __shared__ float t[32][33];
  const float* s = (blockIdx.z == 0) ? s0 : (blockIdx.z == 1) ? s1 : s2;
  unsigned short* dz = d + (size_t)blockIdx.z * R * C;
  int c0 = blockIdx.x * 32, r0 = blockIdx.y * 32;
  int tx = threadIdx.x, ty = threadIdx.y;  // block (32,8)
#pragma unroll
  for (int j = 0; j < 32; j += 8)
    t[ty + j][tx] = s[(size_t)(r0 + ty + j) * C + c0 + tx];
  __syncthreads();
#pragma unroll
  for (int j = 0; j < 32; j += 8)
    dz[(size_t)(c0 + ty + j) * R + r0 + tx] = f2b(t[tx][ty + j]);
}

__global__ void k_tcvt(const float* __restrict__ s, unsigned short* __restrict__ d, int R, int C) {
  __shared__ float t[32][33];
  int c0 = blockIdx.x * 32, r0 = blockIdx.y * 32;
  int tx = threadIdx.x, ty = threadIdx.y;  // block (32,8)
#pragma unroll
  for (int j = 0; j < 32; j += 8)
    t[ty + j][tx] = s[(size_t)(r0 + ty + j) * C + c0 + tx];
  __syncthreads();
#pragma unroll
  for (int j = 0; j < 32; j += 8)
    d[(size_t)(c0 + ty + j) * R + r0 + tx] = f2b(t[tx][ty + j]);
}

// ---------------- fused QKV projection: 3 GEMMs in one launch (z = 0:Q 1:K 2:V) ----------
// A f32 [8192,1024] staged to LDS bf16 via reg loads + cvt_pk.
// BARRIER FIX (r17): bottom WAR barrier is a RAW s_barrier (no vmcnt drain) so the
// A(t+1) prefetch loads issued mid-iter stay in flight across it; __syncthreads
// there was draining vmcnt(0) and exposing full HBM latency every K-iter
// (gemm3 counters: MfmaUtil 16%, VALU 13%, HBM 8% -- pure latency stall).
// Safety: all frag ds_reads complete before each wave's last MFMA (compiler
// lgkmcnt), so reads are done at the barrier; "memory" clobber stops reordering.
__global__ __launch_bounds__(256, 2) void k_gemm3(
    const float* __restrict__ Aq, const float* __restrict__ Ak, const float* __restrict__ Av,
    const unsigned short* __restrict__ Wt3,
    const float* __restrict__ bq, const float* __restrict__ bk, const float* __restrict__ bv,
    unsigned short* __restrict__ Qh, unsigned short* __restrict__ Kh,
    unsigned short* __restrict__ Vtb, float qscale) {
  __shared__ unsigned short Al[128 * 32];
  __shared__ unsigned short Bl[128 * 32];
  const int tid = threadIdx.x, wid = tid >> 6, lane = tid & 63;
  const int m0 = blockIdx.x * 128, n0 = blockIdx.y * 128;
  const int z = blockIdx.z;
  const int wr = wid >> 1, wc = wid & 1;
  const int g = lane >> 4, r16 = lane & 15;
  const int K = DIM;

  const float* Af = (z == 0) ? Aq : (z == 1) ? Ak : Av;
  const unsigned short* Bt = Wt3 + (size_t)z * DIM * DIM;
  const float* bias = (z == 0) ? bq : (z == 1) ? bk : bv;
  const float scale = (z == 0) ? qscale : 1.0f;

  // reg-staging geometry: slot f8 = j*256+tid -> row = f8>>2, col8 = (f8&3)*8
  const int ra = tid >> 2, ca = (tid & 3) * 8;
  const int rb = (256 + tid) >> 2, cb = ((256 + tid) & 3) * 8;
  float4 ar[2][2];
  {
    const float4* pa = reinterpret_cast<const float4*>(Af + (size_t)(m0 + ra) * K + ca);
    const float4* pb = reinterpret_cast<const float4*>(Af + (size_t)(m0 + rb) * K + cb);
    ar[0][0] = pa[0]; ar[0][1] = pa[1];
    ar[1][0] = pb[0]; ar[1][1] = pb[1];
  }

  f32x4 acc[4][4];
#pragma unroll
  for (int i = 0; i < 4; ++i)
#pragma unroll
    for (int j = 0; j < 4; ++j) acc[i][j] = f32x4{0.f, 0.f, 0.f, 0.f};

  for (int kk = 0; kk < K; kk += 32) {
    // stage A from regs (compiler inserts vmcnt wait for ar here)
    u32x4 w0{cvtpk(ar[0][0].x, ar[0][0].y), cvtpk(ar[0][0].z, ar[0][0].w),
             cvtpk(ar[0][1].x, ar[0][1].y), cvtpk(ar[0][1].z, ar[0][1].w)};
    *reinterpret_cast<u32x4*>(&Al[ra * 32 + ca]) = w0;
    u32x4 w1{cvtpk(ar[1][0].x, ar[1][0].y), cvtpk(ar[1][0].z, ar[1][0].w),
             cvtpk(ar[1][1].x, ar[1][1].y), cvtpk(ar[1][1].z, ar[1][1].w)};
    *reinterpret_cast<u32x4*>(&Al[rb * 32 + cb]) = w1;
#pragma unroll
    for (int is = 0; is < 2; ++is) {
      int slot = (is * 4 + wid) * 64 + lane;
      int row = slot >> 2, ch = slot & 3;
      gload16(Bt + (size_t)(n0 + row) * K + kk + ch * 8, &Bl[(is * 4 + wid) * 64 * 8]);
    }
    __syncthreads();  // RAW: A ds_writes (lgkm) + B gloads (vmcnt) visible; no A-prefetch outstanding here
    if (kk + 32 < K) {  // issue next A f32 loads; they stay in flight across the raw WAR barrier
      const float4* pa = reinterpret_cast<const float4*>(Af + (size_t)(m0 + ra) * K + kk + 32 + ca);
      const float4* pb = reinterpret_cast<const float4*>(Af + (size_t)(m0 + rb) * K + kk + 32 + cb);
      ar[0][0] = pa[0]; ar[0][1] = pa[1];
      ar[1][0] = pb[0]; ar[1][1] = pb[1];
    }
    bf16x8 af[4], bfv[4];
#pragma unroll
    for (int i = 0; i < 4; ++i)
      af[i] = *reinterpret_cast<const bf16x8*>(&Al[(wr * 64 + i * 16 + r16) * 32 + g * 8]);
#pragma unroll
    for (int j = 0; j < 4; ++j)
      bfv[j] = *reinterpret_cast<const bf16x8*>(&Bl[(wc * 64 + j * 16 + r16) * 32 + g * 8]);
#pragma unroll
    for (int i = 0; i < 4; ++i)
#pragma unroll
      for (int j = 0; j < 4; ++j)
        acc[i][j] = __builtin_amdgcn_mfma_f32_16x16x32_bf16(af[i], bfv[j], acc[i][j], 0, 0, 0);
    asm volatile("s_barrier" ::: "memory");  // WAR raw barrier: NO vmcnt drain
  }

  const int rr = g * 4;
#pragma unroll
  for (int i = 0; i < 4; ++i) {
#pragma unroll
    for (int j = 0; j < 4; ++j) {
#pragma unroll
      for (int q = 0; q < 4; ++q) {
        int mrow = m0 + wr * 64 + i * 16 + rr + q;
        int ncol = n0 + wc * 64 + j * 16 + r16;
        float v = (acc[i][j][q] + bias[ncol]) * scale;
        int b_ = mrow >> 11, s_ = mrow & 2047;
        int h_ = ncol >> 6, hd = ncol & 63;
        if (z == 2) {
          Vtb[(((size_t)(b_ * NH + h_) * HDIM + hd) << 11) + s_] = f2b(v);
        } else {
          unsigned short* dst = (z == 0) ? Qh : Kh;
          dst[(((size_t)(b_ * NH + h_) * SEQ + s_) << 6) + hd] = f2b(v);
        }
      }
    }
  }
}

// ---------------- final projection: A bf16 [M,K] x Wt [N,K]^T -> f32 [M,N] ----------------
__global__ __launch_bounds__(256, 2) void k_gemmf(
    const unsigned short* __restrict__ A, const unsigned short* __restrict__ Bt,
    const float* __restrict__ bias, float* __restrict__ out, int K, int N) {
  __shared__ unsigned short Al[128 * 32];
  __shared__ unsigned short Bl[128 * 32];
  const int tid = threadIdx.x, wid = tid >> 6, lane = tid & 63;
  const int m0 = blockIdx.x * 128, n0 = blockIdx.y * 128;
  const int wr = wid >> 1, wc = wid & 1;
  const int g = lane >> 4, r16 = lane & 15;

  f32x4 acc[4][4];
#pragma unroll
  for (int i = 0; i < 4; ++i)
#pragma unroll
    for (int j = 0; j < 4; ++j) acc[i][j] = f32x4{0.f, 0.f, 0.f, 0.f};

  for (int kk = 0; kk < K; kk += 32) {
#pragma unroll
    for (int is = 0; is < 2; ++is) {
      int slot = (is * 4 + wid) * 64 + lane;
      int row = slot >> 2, ch = slot & 3;
      gload16(A + (size_t)(m0 + row) * K + kk + ch * 8, &Al[(is * 4 + wid) * 64 * 8]);
    }
#pragma unroll
    for (int is = 0; is < 2; ++is) {
      int slot = (is * 4 + wid) * 64 + lane;
      int row = slot >> 2, ch = slot & 3;
      gload16(Bt + (size_t)(n0 + row) * K + kk + ch * 8, &Bl[(is * 4 + wid) * 64 * 8]);
    }
    __syncthreads();
    bf16x8 af[4], bfv[4];
#pragma unroll
    for (int i = 0; i < 4; ++i)
      af[i] = *reinterpret_cast<const bf16x8*>(&Al[(wr * 64 + i * 16 + r16) * 32 + g * 8]);
#pragma unroll
    for (int j = 0; j < 4; ++j)
      bfv[j] = *reinterpret_cast<const bf16x8*>(&Bl[(wc * 64 + j * 16 + r16) * 32 + g * 8]);
#pragma unroll
    for (int i = 0; i < 4; ++i)
#pragma unroll
      for (int j = 0; j < 4; ++j)
        acc[i][j] = __builtin_amdgcn_mfma_f32_16x16x32_bf16(af[i], bfv[j], acc[i][j], 0, 0, 0);
    __syncthreads();
  }

  const int rr = g * 4;
#pragma unroll
  for (int i = 0; i < 4; ++i)
#pragma unroll
    for (int j = 0; j < 4; ++j)
#pragma unroll
      for (int q = 0; q < 4; ++q) {
        int mrow = m0 + wr * 64 + i * 16 + rr + q;
        int ncol = n0 + wc * 64 + j * 16 + r16;
        out[(size_t)mrow * N + ncol] = acc[i][j][q] + bias[ncol];
      }
}

// ---------------- attention with "+1" sink softmax, NO max subtraction ----------------
// (r14-verified: swapped QK^T, exp2 domain, cvt_pk P-pack, ones-column row sums,
//  single-buffer 32KB LDS, launch_bounds(256,4))
__global__ __launch_bounds__(256, 4) void k_attn(
    const unsigned short* __restrict__ Qh, const unsigned short* __restrict__ Kh,
    const unsigned short* __restrict__ Vt, unsigned short* __restrict__ X) {
  __shared__ unsigned short Kl[64 * 64];   // [kv][hd], chunk-swizzled
  __shared__ unsigned short Vl[64 * 64];   // [hd][kv], chunk-swizzled
  __shared__ unsigned short Pl[128 * 64];  // [q][kv],  chunk-swizzled (wave-private rows)

  const int tid = threadIdx.x, wid = tid >> 6, lane = tid & 63;
  const int g = lane >> 4, r16 = lane & 15;
  const int bh = blockIdx.y, b_ = bh >> 4, h_ = bh & 15;
  const int q0 = blockIdx.x * 128;
  const unsigned short* Qp = Qh + ((size_t)bh * SEQ + q0) * HDIM;
  const unsigned short* Kp = Kh + (size_t)bh * SEQ * HDIM;
  const unsigned short* Vp = Vt + (size_t)bh * HDIM * SEQ;
  const int qw = wid * 32;

  bf16x8 qf[2][2];
#pragma unroll
  for (int fr = 0; fr < 2; ++fr)
#pragma unroll
    for (int ks = 0; ks < 2; ++ks)
      qf[fr][ks] = *reinterpret_cast<const bf16x8*>(
          Qp + (size_t)(qw + fr * 16 + r16) * HDIM + ks * 32 + g * 8);

  bf16x8 vones;
#pragma unroll
  for (int i = 0; i < 8; ++i) vones[i] = (r16 == 0) ? (short)0x3F80 : (short)0;

  const int slot0 = wid * 64 + lane, slot1 = (4 + wid) * 64 + lane;
  const int sr0 = slot0 >> 3, sc0 = (slot0 & 7) ^ (sr0 & 7);
  const int sr1 = slot1 >> 3, sc1 = (slot1 & 7) ^ (sr1 & 7);
  const unsigned short* Ks0 = Kp + (size_t)sr0 * HDIM + sc0 * 8;
  const unsigned short* Ks1 = Kp + (size_t)sr1 * HDIM + sc1 * 8;
  const unsigned short* Vs0 = Vp + (size_t)sr0 * SEQ + sc0 * 8;
  const unsigned short* Vs1 = Vp + (size_t)sr1 * SEQ + sc1 * 8;
  const int ld0 = wid * 512, ld1 = (4 + wid) * 512;

  f32x4 o[2][4], ol[2];
#pragma unroll
  for (int fr = 0; fr < 2; ++fr) {
#pragma unroll
    for (int hf = 0; hf < 4; ++hf) o[fr][hf] = f32x4{0.f, 0.f, 0.f, 0.f};
    ol[fr] = f32x4{0.f, 0.f, 0.f, 0.f};
  }

  for (int t = 0; t < SEQ / 64; ++t) {
    __syncthreads();  // WAR
    {
      const size_t koff = (size_t)t * 64 * HDIM;
      const int voff = t * 64;
      gload16(Ks0 + koff, &Kl[ld0]);
      gload16(Ks1 + koff, &Kl[ld1]);
      gload16(Vs0 + voff, &Vl[ld0]);
      gload16(Vs1 + voff, &Vl[ld1]);
    }
    __syncthreads();  // RAW

    f32x4 s_[2][4];
#pragma unroll
    for (int fr = 0; fr < 2; ++fr)
#pragma unroll
      for (int cf = 0; cf < 4; ++cf) s_[fr][cf] = f32x4{0.f, 0.f, 0.f, 0.f};
#pragma unroll
    for (int cf = 0; cf < 4; ++cf) {
      int krow = cf * 16 + r16;
#pragma unroll
      for (int ks = 0; ks < 2; ++ks) {
        bf16x8 kf = *reinterpret_cast<const bf16x8*>(
            &Kl[krow * 64 + (((ks * 4 + g) ^ (krow & 7)) << 3)]);
#pragma unroll
        for (int fr = 0; fr < 2; ++fr)
          s_[fr][cf] = __builtin_amdgcn_mfma_f32_16x16x32_bf16(kf, qf[fr][ks], s_[fr][cf], 0, 0, 0);
      }
    }

#pragma unroll
    for (int fr = 0; fr < 2; ++fr) {
      int prow = qw + fr * 16 + r16;
      int base = prow * 64, swz = prow & 7;
#pragma unroll
      for (int cf = 0; cf < 4; ++cf) {
        float p0 = ex2(s_[fr][cf][0]);
        float p1 = ex2(s_[fr][cf][1]);
        float p2 = ex2(s_[fr][cf][2]);
        float p3 = ex2(s_[fr][cf][3]);
        unsigned w0 = cvtpk(p0, p1);
        unsigned w1 = cvtpk(p2, p3);
        int off = base + (((cf * 2 + (g >> 1)) ^ swz) << 3) + (g & 1) * 4;
        *reinterpret_cast<u32x2*>(&Pl[off]) = u32x2{w0, w1};
      }
    }

#pragma unroll
    for (int ks = 0; ks < 2; ++ks) {
      bf16x8 pf[2];
#pragma unroll
      for (int fr = 0; fr < 2; ++fr) {
        int prow = qw + fr * 16 + r16;
        pf[fr] = *reinterpret_cast<const bf16x8*>(
            &Pl[prow * 64 + (((ks * 4 + g) ^ (prow & 7)) << 3)]);
      }
#pragma unroll
      for (int hf = 0; hf < 4; ++hf) {
        int vrow = hf * 16 + r16;
        bf16x8 vf = *reinterpret_cast<const bf16x8*>(
            &Vl[vrow * 64 + (((ks * 4 + g) ^ (vrow & 7)) << 3)]);
#pragma unroll
        for (int fr = 0; fr < 2; ++fr)
          o[fr][hf] = __builtin_amdgcn_mfma_f32_16x16x32_bf16(pf[fr], vf, o[fr][hf], 0, 0, 0);
      }
#pragma unroll
      for (int fr = 0; fr < 2; ++fr)
        ol[fr] = __builtin_amdgcn_mfma_f32_16x16x32_bf16(pf[fr], vones, ol[fr], 0, 0, 0);
    }
  }

#pragma unroll
  for (int fr = 0; fr < 2; ++fr) {
#pragma unroll
    for (int q = 0; q < 4; ++q) {
      float lsum = __shfl(ol[fr][q], lane & 48, 64);
      float inv = 1.0f / (1.0f + lsum);
      int row = q0 + qw + fr * 16 + g * 4 + q;
      unsigned short* xp = X + (size_t)(b_ * SEQ + row) * DIM + h_ * 64;
#pragma unroll
      for (int hf = 0; hf < 4; ++hf) xp[hf * 16 + r16] = f2b(o[fr][hf][q] * inv);
    }
  }
}

extern "C" void kernel_launch(void* const* d_in, const int* in_sizes, int n_in,
                              void* d_out, int out_size, void* d_ws, size_t ws_size,
                              hipStream_t stream) {
  const float* q  = (const float*)d_in[0];
  const float* k  = (const float*)d_in[1];
  const float* v  = (const float*)d_in[2];
  const float* Wq = (const float*)d_in[3];
  const float* bq = (const float*)d_in[4];
  const float* Wk = (const float*)d_in[5];
  const float* bk = (const float*)d_in[6];
  const float* Wv = (const float*)d_in[7];
  const float* bv = (const float*)d_in[8];
  const float* Wf = (const float*)d_in[9];
  const float* bf = (const float*)d_in[10];

  char* ws = (char*)d_ws;
  unsigned short* Abuf = (unsigned short*)ws;                              // attn X (8192*1024 bf16)
  unsigned short* Wt3  = (unsigned short*)(ws + (size_t)16777216);         // 3 x 1024x1024 bf16
  unsigned short* Wtf  = Wt3 + (size_t)3 * DIM * DIM;                      // 256x1024 bf16
  unsigned short* Qh   = Wtf + (size_t)DOUT * DIM;
  unsigned short* Kh   = Qh + (size_t)MROWS * DIM;
  unsigned short* Vtb  = Kh + (size_t)MROWS * DIM;

  dim3 b256(256);
  dim3 tb(32, 8);

  const float qscale = 0.125f * 1.44269504088896f;  // 1/sqrt(64) * log2(e): S in log2 units

  // weights: 3 transposes in one launch; final-proj transpose separate
  k_tcvt3<<<dim3(32, 32, 3), tb, 0, stream>>>(Wq, Wk, Wv, Wt3, DIM, DIM);
  k_tcvt<<<dim3(8, 32), tb, 0, stream>>>(Wf, Wtf, DIM, DOUT);
  // fused QKV projection (1536 blocks, cross-GEMM overlap)
  k_gemm3<<<dim3(64, 8, 3), b256, 0, stream>>>(q, k, v, Wt3, bq, bk, bv, Qh, Kh, Vtb, qscale);
  // attention -> X (Abuf)
  k_attn<<<dim3(16, 64), b256, 0, stream>>>(Qh, Kh, Vtb, Abuf);
  // final projection -> f32 out
  k_gemmf<<<dim3(64, 2), b256, 0, stream>>>(Abuf, Wtf, bf, (float*)d_out, DIM, DOUT);
}